// Round 2
// baseline (201.509 us; speedup 1.0000x reference)
//
#include <hip/hip_runtime.h>
#include <hip/hip_bf16.h>

typedef __attribute__((ext_vector_type(8))) short bf16x8;
typedef __attribute__((ext_vector_type(4))) float f32x4;
typedef __attribute__((ext_vector_type(4))) short s16x4;

#define MFMA(a, b, c) __builtin_amdgcn_mfma_f32_16x16x32_bf16(a, b, c, 0, 0, 0)

#define SCALE_F 0.08838834764831845f  // (2*64)^-0.5

__device__ __forceinline__ short f2bf(float f) {
  __hip_bfloat16 h = __float2bfloat16(f);
  return *reinterpret_cast<short*>(&h);
}

__device__ __forceinline__ void gld_lds16(const void* g, void* s) {
  __builtin_amdgcn_global_load_lds(
      (const __attribute__((address_space(1))) void*)g,
      (__attribute__((address_space(3))) void*)s, 16, 0, 0);
}

// ---------------------------------------------------------------------------
// cast fp32 -> bf16 (straight)
__global__ void cast_bf16_kernel(const float* __restrict__ in,
                                 short* __restrict__ out, int n) {
  int i = blockIdx.x * 256 + threadIdx.x;
  int idx = i * 4;
  if (idx < n) {
    float4 v = *(const float4*)&in[idx];
    s16x4 o;
    o.x = f2bf(v.x); o.y = f2bf(v.y); o.z = f2bf(v.z); o.w = f2bf(v.w);
    *(s16x4*)&out[idx] = o;
  }
}

// cast fp32 [R][C] -> bf16 [C][R] (transposed, for B^T GEMM operand)
__global__ void cast_transpose_kernel(const float* __restrict__ in,
                                      short* __restrict__ out, int R, int C) {
  int i = blockIdx.x * 256 + threadIdx.x;
  if (i < R * C) {
    int r = i / C, c = i % C;
    out[(size_t)c * R + r] = f2bf(in[i]);
  }
}

// ---------------------------------------------------------------------------
// GEMM: C[M,N] = A[M,K] (bf16, row-major) @ Bt[N,K]^T (bf16, row-major B^T)
// 128x128 tile, BK=64, 4 waves each 64x64 (4x4 frags of 16x16x32 MFMA).
// MODE 1: qkv epilogue -> C0 = QK buffer [b*2048+n][1024] (cols<1024),
//                         C1 = Vt buffer [(b*8+h)*64+d][2048] (cols>=1024)
// MODE 2: Cf = fp32 out, + bias[col]
template <int MODE>
__global__ __launch_bounds__(256) void gemm_bt(
    const short* __restrict__ A, const short* __restrict__ Bt, int M, int N,
    int K, short* __restrict__ C0, short* __restrict__ C1,
    float* __restrict__ Cf, const float* __restrict__ bias) {
  __shared__ short As[128 * 64];
  __shared__ short Bs[128 * 64];
  const int tid = threadIdx.x;
  const int w = tid >> 6, l = tid & 63;
  const int m0 = blockIdx.x * 128, n0 = blockIdx.y * 128;
  const int mi = (w >> 1) * 64, ni = (w & 1) * 64;
  const int lrow = l & 15, lk8 = (l >> 4) * 8;

  f32x4 acc[4][4] = {};

  for (int k0 = 0; k0 < K; k0 += 64) {
    // stage A and Bt tiles: 1024 16B-chunks each, linear LDS, per-wave groups
    for (int g = 0; g < 4; ++g) {
      int c = g * 256 + w * 64 + l;
      int row = c >> 3, c8 = (c & 7) * 8;
      int ldsoff = (g * 256 + w * 64) * 8;
      gld_lds16(A + (size_t)(m0 + row) * K + k0 + c8, (void*)(As + ldsoff));
      gld_lds16(Bt + (size_t)(n0 + row) * K + k0 + c8, (void*)(Bs + ldsoff));
    }
    __syncthreads();
    for (int kp = 0; kp < 2; ++kp) {
      bf16x8 af[4], bfr[4];
      for (int mf = 0; mf < 4; ++mf)
        af[mf] = *(const bf16x8*)&As[(mi + mf * 16 + lrow) * 64 + kp * 32 + lk8];
      for (int nf = 0; nf < 4; ++nf)
        bfr[nf] = *(const bf16x8*)&Bs[(ni + nf * 16 + lrow) * 64 + kp * 32 + lk8];
      for (int mf = 0; mf < 4; ++mf)
        for (int nf = 0; nf < 4; ++nf)
          acc[mf][nf] = MFMA(af[mf], bfr[nf], acc[mf][nf]);
    }
    __syncthreads();
  }

  // epilogue: C/D layout col=lane&15, row=(lane>>4)*4+reg (guide m89)
  for (int mf = 0; mf < 4; ++mf)
    for (int nf = 0; nf < 4; ++nf)
      for (int r = 0; r < 4; ++r) {
        int row = m0 + mi + mf * 16 + (l >> 4) * 4 + r;
        int col = n0 + ni + nf * 16 + lrow;
        float v = acc[mf][nf][r];
        if (MODE == 1) {
          if (col < 1024) {
            C0[(size_t)row * 1024 + col] = f2bf(v);
          } else {
            int b = row >> 11, n = row & 2047;
            int cv = col - 1024, h = cv >> 6, d = cv & 63;
            C1[(((size_t)(b * 8 + h) * 64 + d) << 11) + n] = f2bf(v);
          }
        } else {
          Cf[(size_t)row * N + col] = v + bias[col];
        }
      }
}

// ---------------------------------------------------------------------------
// Dual-stream flash attention.
// grid: (N/64 q-tiles, B*H). 4 waves, each owns 16 q-rows.
// QK buffers: [b*2048+n][1024] (Q cols 0..511, K cols 512..1023), per head 64.
// Vt buffers: [(b*8+h)*64+d][2048].
// Writes Ocat[b*4096 + n][512] (stream1) and [b*4096 + 2048 + n][512] (stream2).
__global__ __launch_bounds__(256) void attn_kernel(
    const short* __restrict__ QK1, const short* __restrict__ QK2,
    const short* __restrict__ Vt1, const short* __restrict__ Vt2,
    short* __restrict__ Ocat) {
  __shared__ short K1s[64 * 64], K2s[64 * 64], V1s[64 * 64], V2s[64 * 64];
  __shared__ short Ps[64 * 72];

  const int tid = threadIdx.x;
  const int w = tid >> 6, l = tid & 63;
  const int qb = blockIdx.x, bh = blockIdx.y;
  const int b = bh >> 3, h = bh & 7;
  const int lrow = l & 15, lk8 = (l >> 4) * 8;

  const short* Q1p = QK1 + (size_t)b * 2048 * 1024 + h * 64;
  const short* K1p = Q1p + 512;
  const short* Q2p = QK2 + (size_t)b * 2048 * 1024 + h * 64;
  const short* K2p = Q2p + 512;
  const short* V1p = Vt1 + (size_t)bh * 64 * 2048;
  const short* V2p = Vt2 + (size_t)bh * 64 * 2048;

  // Q fragments live in registers for the whole kernel
  const int qrow = qb * 64 + w * 16 + lrow;
  bf16x8 q1f[2], q2f[2];
  q1f[0] = *(const bf16x8*)&Q1p[(size_t)qrow * 1024 + lk8];
  q1f[1] = *(const bf16x8*)&Q1p[(size_t)qrow * 1024 + 32 + lk8];
  q2f[0] = *(const bf16x8*)&Q2p[(size_t)qrow * 1024 + lk8];
  q2f[1] = *(const bf16x8*)&Q2p[(size_t)qrow * 1024 + 32 + lk8];

  f32x4 o1[4] = {}, o2[4] = {};
  float mrun[4], lrun[4];
  for (int r = 0; r < 4; ++r) { mrun[r] = -1e30f; lrun[r] = 0.f; }

  for (int kt = 0; kt < 32; ++kt) {
    const int kv0 = kt * 64;
    // stage K1,K2 (row-major [krow][64]) and V1t,V2t ([d][64]) tiles
    for (int g = 0; g < 2; ++g) {
      int c = g * 256 + w * 64 + l;
      int row = c >> 3, c8 = (c & 7) * 8;
      int ldsoff = (g * 256 + w * 64) * 8;
      gld_lds16(K1p + (size_t)(kv0 + row) * 1024 + c8, (void*)(K1s + ldsoff));
      gld_lds16(K2p + (size_t)(kv0 + row) * 1024 + c8, (void*)(K2s + ldsoff));
      gld_lds16(V1p + (size_t)row * 2048 + kv0 + c8, (void*)(V1s + ldsoff));
      gld_lds16(V2p + (size_t)row * 2048 + kv0 + c8, (void*)(V2s + ldsoff));
    }
    __syncthreads();

    // S = Q1 K1^T + Q2 K2^T  (accumulate both streams into same acc)
    f32x4 s[4] = {};
    for (int nf = 0; nf < 4; ++nf) {
      bf16x8 k1a = *(const bf16x8*)&K1s[(nf * 16 + lrow) * 64 + lk8];
      bf16x8 k1b = *(const bf16x8*)&K1s[(nf * 16 + lrow) * 64 + 32 + lk8];
      bf16x8 k2a = *(const bf16x8*)&K2s[(nf * 16 + lrow) * 64 + lk8];
      bf16x8 k2b = *(const bf16x8*)&K2s[(nf * 16 + lrow) * 64 + 32 + lk8];
      s[nf] = MFMA(q1f[0], k1a, s[nf]);
      s[nf] = MFMA(q1f[1], k1b, s[nf]);
      s[nf] = MFMA(q2f[0], k2a, s[nf]);
      s[nf] = MFMA(q2f[1], k2b, s[nf]);
    }

    // online softmax: each lane owns rows (l>>4)*4+r, replicated over 16 lanes
    for (int r = 0; r < 4; ++r) {
      float t0 = s[0][r] * SCALE_F, t1 = s[1][r] * SCALE_F;
      float t2 = s[2][r] * SCALE_F, t3 = s[3][r] * SCALE_F;
      float mx = fmaxf(fmaxf(t0, t1), fmaxf(t2, t3));
      for (int off = 1; off < 16; off <<= 1) mx = fmaxf(mx, __shfl_xor(mx, off, 16));
      float newm = fmaxf(mrun[r], mx);
      float corr = __expf(mrun[r] - newm);
      mrun[r] = newm;
      float p0 = __expf(t0 - newm), p1 = __expf(t1 - newm);
      float p2 = __expf(t2 - newm), p3 = __expf(t3 - newm);
      float psum = p0 + p1 + p2 + p3;
      for (int off = 1; off < 16; off <<= 1) psum += __shfl_xor(psum, off, 16);
      lrun[r] = lrun[r] * corr + psum;
      int prow = (w * 16 + (l >> 4) * 4 + r) * 72 + lrow;
      Ps[prow + 0] = f2bf(p0);
      Ps[prow + 16] = f2bf(p1);
      Ps[prow + 32] = f2bf(p2);
      Ps[prow + 48] = f2bf(p3);
      for (int nf = 0; nf < 4; ++nf) { o1[nf][r] *= corr; o2[nf][r] *= corr; }
    }

    // PV: O += P @ V (P rows are wave-private, no barrier needed)
    bf16x8 pa0 = *(const bf16x8*)&Ps[(w * 16 + lrow) * 72 + lk8];
    bf16x8 pa1 = *(const bf16x8*)&Ps[(w * 16 + lrow) * 72 + 32 + lk8];
    for (int nf = 0; nf < 4; ++nf) {
      bf16x8 v1a = *(const bf16x8*)&V1s[(nf * 16 + lrow) * 64 + lk8];
      bf16x8 v1b = *(const bf16x8*)&V1s[(nf * 16 + lrow) * 64 + 32 + lk8];
      bf16x8 v2a = *(const bf16x8*)&V2s[(nf * 16 + lrow) * 64 + lk8];
      bf16x8 v2b = *(const bf16x8*)&V2s[(nf * 16 + lrow) * 64 + 32 + lk8];
      o1[nf] = MFMA(pa0, v1a, o1[nf]);
      o1[nf] = MFMA(pa1, v1b, o1[nf]);
      o2[nf] = MFMA(pa0, v2a, o2[nf]);
      o2[nf] = MFMA(pa1, v2b, o2[nf]);
    }
    __syncthreads();
  }

  // epilogue: normalize and write merged layout [b, n, h*64+d]
  for (int r = 0; r < 4; ++r) {
    float inv = 1.0f / lrun[r];
    int row = qb * 64 + w * 16 + (l >> 4) * 4 + r;
    for (int nf = 0; nf < 4; ++nf) {
      int col = h * 64 + nf * 16 + lrow;
      Ocat[((size_t)b * 4096 + row) * 512 + col] = f2bf(o1[nf][r] * inv);
      Ocat[((size_t)b * 4096 + 2048 + row) * 512 + col] = f2bf(o2[nf][r] * inv);
    }
  }
}

// ---------------------------------------------------------------------------
extern "C" void kernel_launch(void* const* d_in, const int* in_sizes, int n_in,
                              void* d_out, int out_size, void* d_ws,
                              size_t ws_size, hipStream_t stream) {
  const float* x1 = (const float*)d_in[0];
  const float* x2 = (const float*)d_in[1];
  const float* Wq1 = (const float*)d_in[2];
  const float* Wq2 = (const float*)d_in[3];
  const float* Wo = (const float*)d_in[4];
  const float* bo = (const float*)d_in[5];
  float* out = (float*)d_out;

  // workspace layout (bf16 elements); total ~45.6 MB
  short* p = (short*)d_ws;
  short* xb1 = p;  p += (size_t)4096 * 512;
  short* xb2 = p;  p += (size_t)4096 * 512;
  short* W1t = p;  p += (size_t)1536 * 512;
  short* W2t = p;  p += (size_t)1536 * 512;
  short* Wot = p;  p += (size_t)512 * 512;
  short* QK1 = p;  p += (size_t)4096 * 1024;
  short* QK2 = p;  p += (size_t)4096 * 1024;
  short* Vt1 = p;  p += (size_t)2 * 8 * 64 * 2048;
  short* Vt2 = p;  p += (size_t)2 * 8 * 64 * 2048;
  short* Ocat = p; p += (size_t)8192 * 512;

  cast_bf16_kernel<<<2048, 256, 0, stream>>>(x1, xb1, 4096 * 512);
  cast_bf16_kernel<<<2048, 256, 0, stream>>>(x2, xb2, 4096 * 512);
  cast_transpose_kernel<<<(512 * 1536 + 255) / 256, 256, 0, stream>>>(Wq1, W1t, 512, 1536);
  cast_transpose_kernel<<<(512 * 1536 + 255) / 256, 256, 0, stream>>>(Wq2, W2t, 512, 1536);
  cast_transpose_kernel<<<(512 * 512 + 255) / 256, 256, 0, stream>>>(Wo, Wot, 512, 512);

  gemm_bt<1><<<dim3(32, 12), 256, 0, stream>>>(xb1, W1t, 4096, 1536, 512, QK1,
                                               Vt1, nullptr, nullptr);
  gemm_bt<1><<<dim3(32, 12), 256, 0, stream>>>(xb2, W2t, 4096, 1536, 512, QK2,
                                               Vt2, nullptr, nullptr);

  attn_kernel<<<dim3(32, 16), 256, 0, stream>>>(QK1, QK2, Vt1, Vt2, Ocat);

  gemm_bt<2><<<dim3(64, 4), 256, 0, stream>>>(Ocat, Wot, 8192, 512, 512,
                                              nullptr, nullptr, out, bo);
}

// Round 3
// 173.453 us; speedup vs baseline: 1.1617x; 1.1617x over previous
//
#include <hip/hip_runtime.h>
#include <hip/hip_bf16.h>

typedef __attribute__((ext_vector_type(8))) short bf16x8;
typedef __attribute__((ext_vector_type(4))) float f32x4;
typedef __attribute__((ext_vector_type(4))) short s16x4;

#define MFMA(a, b, c) __builtin_amdgcn_mfma_f32_16x16x32_bf16(a, b, c, 0, 0, 0)

#define SCALE_F 0.08838834764831845f  // (2*64)^-0.5

__device__ __forceinline__ short f2bf(float f) {
  __hip_bfloat16 h = __float2bfloat16(f);
  return *reinterpret_cast<short*>(&h);
}

__device__ __forceinline__ void gld_lds16(const void* g, void* s) {
  __builtin_amdgcn_global_load_lds(
      (const __attribute__((address_space(1))) void*)g,
      (__attribute__((address_space(3))) void*)s, 16, 0, 0);
}

// ---------------------------------------------------------------------------
// cast fp32 -> bf16, two tensors in one launch
__global__ void cast_bf16_dual(const float* __restrict__ a,
                               const float* __restrict__ b,
                               short* __restrict__ oa, short* __restrict__ ob,
                               int n) {
  int idx = (blockIdx.x * 256 + threadIdx.x) * 4;
  const float* src = a;
  short* dst = oa;
  if (idx >= n) { idx -= n; src = b; dst = ob; }
  float4 v = *(const float4*)&src[idx];
  s16x4 o;
  o.x = f2bf(v.x); o.y = f2bf(v.y); o.z = f2bf(v.z); o.w = f2bf(v.w);
  *(s16x4*)&dst[idx] = o;
}

// cast fp32 [R][C] -> bf16 [C][R], two tensors in one launch
__global__ void cast_transpose_dual(const float* __restrict__ a,
                                    const float* __restrict__ b,
                                    short* __restrict__ oa,
                                    short* __restrict__ ob, int R, int C) {
  int i = blockIdx.x * 256 + threadIdx.x;
  const float* src = a;
  short* dst = oa;
  if (i >= R * C) { i -= R * C; src = b; dst = ob; }
  int r = i / C, c = i % C;
  dst[(size_t)c * R + r] = f2bf(src[i]);
}

__global__ void cast_transpose_kernel(const float* __restrict__ in,
                                      short* __restrict__ out, int R, int C) {
  int i = blockIdx.x * 256 + threadIdx.x;
  if (i < R * C) {
    int r = i / C, c = i % C;
    out[(size_t)c * R + r] = f2bf(in[i]);
  }
}

// ---------------------------------------------------------------------------
// GEMM: C[M,N] = A[M,K] (bf16, row-major) @ Bt[N,K]^T (bf16, row-major B^T)
// 128x128 tile, BK=64, 4 waves each 64x64 (4x4 frags of 16x16x32 MFMA).
// MODE 1: qkv epilogue -> C0 = QK buffer [b*2048+n][1024] (cols<1024),
//                         C1 = Vt buffer [(b*8+h)*64+d][2048] (cols>=1024)
// MODE 2: Cf = fp32 out, + bias[col]
template <int MODE>
__global__ __launch_bounds__(256) void gemm_bt(
    const short* __restrict__ A, const short* __restrict__ Bt, int M, int N,
    int K, short* __restrict__ C0, short* __restrict__ C1,
    float* __restrict__ Cf, const float* __restrict__ bias) {
  __shared__ short As[128 * 64];
  __shared__ short Bs[128 * 64];
  const int tid = threadIdx.x;
  const int w = tid >> 6, l = tid & 63;
  const int m0 = blockIdx.x * 128, n0 = blockIdx.y * 128;
  const int mi = (w >> 1) * 64, ni = (w & 1) * 64;
  const int lrow = l & 15, lk8 = (l >> 4) * 8;

  f32x4 acc[4][4] = {};

  for (int k0 = 0; k0 < K; k0 += 64) {
    for (int g = 0; g < 4; ++g) {
      int c = g * 256 + w * 64 + l;
      int row = c >> 3, c8 = (c & 7) * 8;
      int ldsoff = (g * 256 + w * 64) * 8;
      gld_lds16(A + (size_t)(m0 + row) * K + k0 + c8, (void*)(As + ldsoff));
      gld_lds16(Bt + (size_t)(n0 + row) * K + k0 + c8, (void*)(Bs + ldsoff));
    }
    __syncthreads();
    for (int kp = 0; kp < 2; ++kp) {
      bf16x8 af[4], bfr[4];
      for (int mf = 0; mf < 4; ++mf)
        af[mf] = *(const bf16x8*)&As[(mi + mf * 16 + lrow) * 64 + kp * 32 + lk8];
      for (int nf = 0; nf < 4; ++nf)
        bfr[nf] = *(const bf16x8*)&Bs[(ni + nf * 16 + lrow) * 64 + kp * 32 + lk8];
      for (int mf = 0; mf < 4; ++mf)
        for (int nf = 0; nf < 4; ++nf)
          acc[mf][nf] = MFMA(af[mf], bfr[nf], acc[mf][nf]);
    }
    __syncthreads();
  }

  for (int mf = 0; mf < 4; ++mf)
    for (int nf = 0; nf < 4; ++nf)
      for (int r = 0; r < 4; ++r) {
        int row = m0 + mi + mf * 16 + (l >> 4) * 4 + r;
        int col = n0 + ni + nf * 16 + lrow;
        float v = acc[mf][nf][r];
        if (MODE == 1) {
          if (col < 1024) {
            C0[(size_t)row * 1024 + col] = f2bf(v);
          } else {
            int b = row >> 11, n = row & 2047;
            int cv = col - 1024, h = cv >> 6, d = cv & 63;
            C1[(((size_t)(b * 8 + h) * 64 + d) << 11) + n] = f2bf(v);
          }
        } else {
          Cf[(size_t)row * N + col] = v + bias[col];
        }
      }
}

// ---------------------------------------------------------------------------
// Dual-stream flash attention, v2: XOR-swizzled K/V LDS + 2-phase prefetch.
// grid: (N/64 q-tiles, B*H). 4 waves, each owns 16 q-rows.
// LDS tile layout: [row][64] shorts; 16B chunk at (row, pos) holds logical
// chunk lc = pos ^ (row&7) of that row (swizzle applied on the GLOBAL source
// per rule-21; LDS dest of global_load_lds stays linear). Fragment reads
// apply the same involution -> conflict-free floor (8 lanes/bank-quad).
__global__ __launch_bounds__(256) void attn_kernel(
    const short* __restrict__ QK1, const short* __restrict__ QK2,
    const short* __restrict__ Vt1, const short* __restrict__ Vt2,
    short* __restrict__ Ocat) {
  __shared__ short K1s[2][4096], K2s[2][4096], V1s[2][4096], V2s[2][4096];
  __shared__ short Ps[64 * 72];

  const int tid = threadIdx.x;
  const int w = tid >> 6, l = tid & 63;
  const int qb = blockIdx.x, bh = blockIdx.y;
  const int b = bh >> 3, h = bh & 7;
  const int lrow = l & 15, g4 = l >> 4, lk8 = g4 * 8;

  const short* Q1p = QK1 + (size_t)b * 2048 * 1024 + h * 64;
  const short* K1p = Q1p + 512;
  const short* Q2p = QK2 + (size_t)b * 2048 * 1024 + h * 64;
  const short* K2p = Q2p + 512;
  const short* V1p = Vt1 + (size_t)bh * 64 * 2048;
  const short* V2p = Vt2 + (size_t)bh * 64 * 2048;

  // Q fragments live in registers for the whole kernel
  const int qrow = qb * 64 + w * 16 + lrow;
  bf16x8 q1f[2], q2f[2];
  q1f[0] = *(const bf16x8*)&Q1p[(size_t)qrow * 1024 + lk8];
  q1f[1] = *(const bf16x8*)&Q1p[(size_t)qrow * 1024 + 32 + lk8];
  q2f[0] = *(const bf16x8*)&Q2p[(size_t)qrow * 1024 + lk8];
  q2f[1] = *(const bf16x8*)&Q2p[(size_t)qrow * 1024 + 32 + lk8];

  f32x4 o1[4] = {}, o2[4] = {};
  float mrun[4], lrun[4];
  for (int r = 0; r < 4; ++r) { mrun[r] = -1e30f; lrun[r] = 0.f; }

  // stage tile kt into buffer buf (pre-swizzled global source, linear LDS dst)
  auto stage = [&](int buf, int kt) {
    const int kv0 = kt * 64;
    for (int g = 0; g < 2; ++g) {
      int cl = g * 256 + w * 64 + l;  // LDS 16B-chunk index, linear
      int row = cl >> 3;
      int lc = (cl & 7) ^ (row & 7);  // logical chunk fetched into this slot
      int ldsoff = cl * 8;
      gld_lds16(K1p + (size_t)(kv0 + row) * 1024 + lc * 8, (void*)(&K1s[buf][ldsoff]));
      gld_lds16(K2p + (size_t)(kv0 + row) * 1024 + lc * 8, (void*)(&K2s[buf][ldsoff]));
      gld_lds16(V1p + (size_t)row * 2048 + kv0 + lc * 8, (void*)(&V1s[buf][ldsoff]));
      gld_lds16(V2p + (size_t)row * 2048 + kv0 + lc * 8, (void*)(&V2s[buf][ldsoff]));
    }
  };
  // swizzled short-offset of logical chunk kc within row
  auto sw = [&](int row, int kc) { return row * 64 + ((kc ^ (row & 7)) * 8); };

  int cur = 0;
  stage(0, 0);
  __syncthreads();

  for (int kt = 0; kt < 32; ++kt) {
    if (kt + 1 < 32) stage(cur ^ 1, kt + 1);  // prefetch overlaps compute

    // S = Q1 K1^T + Q2 K2^T
    f32x4 s[4] = {};
    for (int nf = 0; nf < 4; ++nf) {
      int row = nf * 16 + lrow;
      bf16x8 k1a = *(const bf16x8*)&K1s[cur][sw(row, g4)];
      bf16x8 k1b = *(const bf16x8*)&K1s[cur][sw(row, 4 + g4)];
      bf16x8 k2a = *(const bf16x8*)&K2s[cur][sw(row, g4)];
      bf16x8 k2b = *(const bf16x8*)&K2s[cur][sw(row, 4 + g4)];
      s[nf] = MFMA(q1f[0], k1a, s[nf]);
      s[nf] = MFMA(q1f[1], k1b, s[nf]);
      s[nf] = MFMA(q2f[0], k2a, s[nf]);
      s[nf] = MFMA(q2f[1], k2b, s[nf]);
    }

    // online softmax: lane owns rows (l>>4)*4+r, replicated over 16 lanes
    for (int r = 0; r < 4; ++r) {
      float t0 = s[0][r] * SCALE_F, t1 = s[1][r] * SCALE_F;
      float t2 = s[2][r] * SCALE_F, t3 = s[3][r] * SCALE_F;
      float mx = fmaxf(fmaxf(t0, t1), fmaxf(t2, t3));
      for (int off = 1; off < 16; off <<= 1) mx = fmaxf(mx, __shfl_xor(mx, off, 16));
      float newm = fmaxf(mrun[r], mx);
      float corr = __expf(mrun[r] - newm);
      mrun[r] = newm;
      float p0 = __expf(t0 - newm), p1 = __expf(t1 - newm);
      float p2 = __expf(t2 - newm), p3 = __expf(t3 - newm);
      float psum = p0 + p1 + p2 + p3;
      for (int off = 1; off < 16; off <<= 1) psum += __shfl_xor(psum, off, 16);
      lrun[r] = lrun[r] * corr + psum;
      int prow = (w * 16 + g4 * 4 + r) * 72 + lrow;
      Ps[prow + 0] = f2bf(p0);
      Ps[prow + 16] = f2bf(p1);
      Ps[prow + 32] = f2bf(p2);
      Ps[prow + 48] = f2bf(p3);
      for (int nf = 0; nf < 4; ++nf) { o1[nf][r] *= corr; o2[nf][r] *= corr; }
    }

    // PV: O += P @ V (P rows are wave-private, no barrier needed)
    bf16x8 pa0 = *(const bf16x8*)&Ps[(w * 16 + lrow) * 72 + lk8];
    bf16x8 pa1 = *(const bf16x8*)&Ps[(w * 16 + lrow) * 72 + 32 + lk8];
    for (int nf = 0; nf < 4; ++nf) {
      int row = nf * 16 + lrow;
      bf16x8 v1a = *(const bf16x8*)&V1s[cur][sw(row, g4)];
      bf16x8 v1b = *(const bf16x8*)&V1s[cur][sw(row, 4 + g4)];
      bf16x8 v2a = *(const bf16x8*)&V2s[cur][sw(row, g4)];
      bf16x8 v2b = *(const bf16x8*)&V2s[cur][sw(row, 4 + g4)];
      o1[nf] = MFMA(pa0, v1a, o1[nf]);
      o1[nf] = MFMA(pa1, v1b, o1[nf]);
      o2[nf] = MFMA(pa0, v2a, o2[nf]);
      o2[nf] = MFMA(pa1, v2b, o2[nf]);
    }
    __syncthreads();  // next tile staged AND everyone done with cur
    cur ^= 1;
  }

  // epilogue: normalize and write merged layout [b, n, h*64+d]
  for (int r = 0; r < 4; ++r) {
    float inv = 1.0f / lrun[r];
    int row = qb * 64 + w * 16 + g4 * 4 + r;
    for (int nf = 0; nf < 4; ++nf) {
      int col = h * 64 + nf * 16 + lrow;
      Ocat[((size_t)b * 4096 + row) * 512 + col] = f2bf(o1[nf][r] * inv);
      Ocat[((size_t)b * 4096 + 2048 + row) * 512 + col] = f2bf(o2[nf][r] * inv);
    }
  }
}

// ---------------------------------------------------------------------------
extern "C" void kernel_launch(void* const* d_in, const int* in_sizes, int n_in,
                              void* d_out, int out_size, void* d_ws,
                              size_t ws_size, hipStream_t stream) {
  const float* x1 = (const float*)d_in[0];
  const float* x2 = (const float*)d_in[1];
  const float* Wq1 = (const float*)d_in[2];
  const float* Wq2 = (const float*)d_in[3];
  const float* Wo = (const float*)d_in[4];
  const float* bo = (const float*)d_in[5];
  float* out = (float*)d_out;

  // workspace layout (bf16 elements); total ~45.6 MB
  short* p = (short*)d_ws;
  short* xb1 = p;  p += (size_t)4096 * 512;
  short* xb2 = p;  p += (size_t)4096 * 512;
  short* W1t = p;  p += (size_t)1536 * 512;
  short* W2t = p;  p += (size_t)1536 * 512;
  short* Wot = p;  p += (size_t)512 * 512;
  short* QK1 = p;  p += (size_t)4096 * 1024;
  short* QK2 = p;  p += (size_t)4096 * 1024;
  short* Vt1 = p;  p += (size_t)2 * 8 * 64 * 2048;
  short* Vt2 = p;  p += (size_t)2 * 8 * 64 * 2048;
  short* Ocat = p; p += (size_t)8192 * 512;

  cast_bf16_dual<<<4096, 256, 0, stream>>>(x1, x2, xb1, xb2, 4096 * 512);
  cast_transpose_dual<<<(2 * 512 * 1536 + 255) / 256, 256, 0, stream>>>(
      Wq1, Wq2, W1t, W2t, 512, 1536);
  cast_transpose_kernel<<<(512 * 512 + 255) / 256, 256, 0, stream>>>(Wo, Wot,
                                                                     512, 512);

  gemm_bt<1><<<dim3(32, 12), 256, 0, stream>>>(xb1, W1t, 4096, 1536, 512, QK1,
                                               Vt1, nullptr, nullptr);
  gemm_bt<1><<<dim3(32, 12), 256, 0, stream>>>(xb2, W2t, 4096, 1536, 512, QK2,
                                               Vt2, nullptr, nullptr);

  attn_kernel<<<dim3(32, 16), 256, 0, stream>>>(QK1, QK2, Vt1, Vt2, Ocat);

  gemm_bt<2><<<dim3(64, 4), 256, 0, stream>>>(Ocat, Wot, 8192, 512, 512,
                                              nullptr, nullptr, out, bo);
}

// Round 4
// 130.988 us; speedup vs baseline: 1.5384x; 1.3242x over previous
//
#include <hip/hip_runtime.h>
#include <hip/hip_bf16.h>

typedef __attribute__((ext_vector_type(8))) short bf16x8;
typedef __attribute__((ext_vector_type(4))) float f32x4;
typedef __attribute__((ext_vector_type(4))) short s16x4;

#define MFMA(a, b, c) __builtin_amdgcn_mfma_f32_16x16x32_bf16(a, b, c, 0, 0, 0)

#define SCALE_F 0.08838834764831845f  // (2*64)^-0.5

__device__ __forceinline__ short f2bf(float f) {
  __hip_bfloat16 h = __float2bfloat16(f);
  return *reinterpret_cast<short*>(&h);
}

__device__ __forceinline__ void gld_lds16(const void* g, void* s) {
  __builtin_amdgcn_global_load_lds(
      (const __attribute__((address_space(1))) void*)g,
      (__attribute__((address_space(3))) void*)s, 16, 0, 0);
}

// ---------------------------------------------------------------------------
// cast fp32 -> bf16, two tensors in one launch
__global__ void cast_bf16_dual(const float* __restrict__ a,
                               const float* __restrict__ b,
                               short* __restrict__ oa, short* __restrict__ ob,
                               int n) {
  int idx = (blockIdx.x * 256 + threadIdx.x) * 4;
  const float* src = a;
  short* dst = oa;
  if (idx >= n) { idx -= n; src = b; dst = ob; }
  float4 v = *(const float4*)&src[idx];
  s16x4 o;
  o.x = f2bf(v.x); o.y = f2bf(v.y); o.z = f2bf(v.z); o.w = f2bf(v.w);
  *(s16x4*)&dst[idx] = o;
}

// cast fp32 [R][C] -> bf16 [C][R], two tensors in one launch
__global__ void cast_transpose_dual(const float* __restrict__ a,
                                    const float* __restrict__ b,
                                    short* __restrict__ oa,
                                    short* __restrict__ ob, int R, int C) {
  int i = blockIdx.x * 256 + threadIdx.x;
  const float* src = a;
  short* dst = oa;
  if (i >= R * C) { i -= R * C; src = b; dst = ob; }
  int r = i / C, c = i % C;
  dst[(size_t)c * R + r] = f2bf(src[i]);
}

__global__ void cast_transpose_kernel(const float* __restrict__ in,
                                      short* __restrict__ out, int R, int C) {
  int i = blockIdx.x * 256 + threadIdx.x;
  if (i < R * C) {
    int r = i / C, c = i % C;
    out[(size_t)c * R + r] = f2bf(in[i]);
  }
}

// ---------------------------------------------------------------------------
// Merged dual-stream QKV GEMM: C = x @ Wqkv for both streams in one launch.
// grid (32, 24): blockIdx.y < 12 -> stream 1, else stream 2.
// 128x128 tile, BK=64, 4 waves each 64x64 (4x4 frags of 16x16x32 MFMA).
// Epilogue: cols<1024 -> QK buffer [b*2048+n][1024];
//           cols>=1024 -> Vt buffer [(b*8+h)*64+d][2048]
__global__ __launch_bounds__(256) void gemm_qkv(
    const short* __restrict__ xb1, const short* __restrict__ xb2,
    const short* __restrict__ W1t, const short* __restrict__ W2t,
    short* __restrict__ QK1, short* __restrict__ QK2,
    short* __restrict__ Vt1, short* __restrict__ Vt2) {
  __shared__ short As[128 * 64];
  __shared__ short Bs[128 * 64];
  const int tid = threadIdx.x;
  const int w = tid >> 6, l = tid & 63;
  const int sid = blockIdx.y >= 12;
  const short* A = sid ? xb2 : xb1;
  const short* Bt = sid ? W2t : W1t;
  short* C0 = sid ? QK2 : QK1;
  short* C1 = sid ? Vt2 : Vt1;
  const int m0 = blockIdx.x * 128;
  const int n0 = (sid ? blockIdx.y - 12 : blockIdx.y) * 128;
  const int mi = (w >> 1) * 64, ni = (w & 1) * 64;
  const int lrow = l & 15, lk8 = (l >> 4) * 8;
  const int K = 512;

  f32x4 acc[4][4] = {};

  for (int k0 = 0; k0 < K; k0 += 64) {
    for (int g = 0; g < 4; ++g) {
      int c = g * 256 + w * 64 + l;
      int row = c >> 3, c8 = (c & 7) * 8;
      int ldsoff = (g * 256 + w * 64) * 8;
      gld_lds16(A + (size_t)(m0 + row) * K + k0 + c8, (void*)(As + ldsoff));
      gld_lds16(Bt + (size_t)(n0 + row) * K + k0 + c8, (void*)(Bs + ldsoff));
    }
    __syncthreads();
    __builtin_amdgcn_s_setprio(1);
    for (int kp = 0; kp < 2; ++kp) {
      bf16x8 af[4], bfr[4];
      for (int mf = 0; mf < 4; ++mf)
        af[mf] = *(const bf16x8*)&As[(mi + mf * 16 + lrow) * 64 + kp * 32 + lk8];
      for (int nf = 0; nf < 4; ++nf)
        bfr[nf] = *(const bf16x8*)&Bs[(ni + nf * 16 + lrow) * 64 + kp * 32 + lk8];
      for (int mf = 0; mf < 4; ++mf)
        for (int nf = 0; nf < 4; ++nf)
          acc[mf][nf] = MFMA(af[mf], bfr[nf], acc[mf][nf]);
    }
    __builtin_amdgcn_s_setprio(0);
    __syncthreads();
  }

  for (int mf = 0; mf < 4; ++mf)
    for (int nf = 0; nf < 4; ++nf)
      for (int r = 0; r < 4; ++r) {
        int row = m0 + mi + mf * 16 + (l >> 4) * 4 + r;
        int col = n0 + ni + nf * 16 + lrow;
        float v = acc[mf][nf][r];
        if (col < 1024) {
          C0[(size_t)row * 1024 + col] = f2bf(v);
        } else {
          int b = row >> 11, n = row & 2047;
          int cv = col - 1024, h = cv >> 6, d = cv & 63;
          C1[(((size_t)(b * 8 + h) * 64 + d) << 11) + n] = f2bf(v);
        }
      }
}

// ---------------------------------------------------------------------------
// Output-projection GEMM: Cf[M,N] = A[M,K] @ Wot[N,K]^T + bias
__global__ __launch_bounds__(256) void gemm_out(
    const short* __restrict__ A, const short* __restrict__ Bt, int M, int N,
    int K, float* __restrict__ Cf, const float* __restrict__ bias) {
  __shared__ short As[128 * 64];
  __shared__ short Bs[128 * 64];
  const int tid = threadIdx.x;
  const int w = tid >> 6, l = tid & 63;
  const int m0 = blockIdx.x * 128, n0 = blockIdx.y * 128;
  const int mi = (w >> 1) * 64, ni = (w & 1) * 64;
  const int lrow = l & 15, lk8 = (l >> 4) * 8;

  f32x4 acc[4][4] = {};

  for (int k0 = 0; k0 < K; k0 += 64) {
    for (int g = 0; g < 4; ++g) {
      int c = g * 256 + w * 64 + l;
      int row = c >> 3, c8 = (c & 7) * 8;
      int ldsoff = (g * 256 + w * 64) * 8;
      gld_lds16(A + (size_t)(m0 + row) * K + k0 + c8, (void*)(As + ldsoff));
      gld_lds16(Bt + (size_t)(n0 + row) * K + k0 + c8, (void*)(Bs + ldsoff));
    }
    __syncthreads();
    __builtin_amdgcn_s_setprio(1);
    for (int kp = 0; kp < 2; ++kp) {
      bf16x8 af[4], bfr[4];
      for (int mf = 0; mf < 4; ++mf)
        af[mf] = *(const bf16x8*)&As[(mi + mf * 16 + lrow) * 64 + kp * 32 + lk8];
      for (int nf = 0; nf < 4; ++nf)
        bfr[nf] = *(const bf16x8*)&Bs[(ni + nf * 16 + lrow) * 64 + kp * 32 + lk8];
      for (int mf = 0; mf < 4; ++mf)
        for (int nf = 0; nf < 4; ++nf)
          acc[mf][nf] = MFMA(af[mf], bfr[nf], acc[mf][nf]);
    }
    __builtin_amdgcn_s_setprio(0);
    __syncthreads();
  }

  for (int mf = 0; mf < 4; ++mf)
    for (int nf = 0; nf < 4; ++nf)
      for (int r = 0; r < 4; ++r) {
        int row = m0 + mi + mf * 16 + (l >> 4) * 4 + r;
        int col = n0 + ni + nf * 16 + lrow;
        Cf[(size_t)row * N + col] = acc[mf][nf][r] + bias[col];
      }
}

// ---------------------------------------------------------------------------
// Dual-stream flash attention, v3: swapped QK^T (S^T in regs) -> in-register
// softmax (2 shuffles per reduction instead of 32/iter), defer-max rescale,
// swapped PV (O^T), setprio around MFMA clusters.
// grid: (N/64 q-tiles, B*H). 4 waves, each owns 16 q-rows.
// K/V LDS tiles XOR-swizzled via pre-swizzled global source (rule 21).
__global__ __launch_bounds__(256) void attn_kernel(
    const short* __restrict__ QK1, const short* __restrict__ QK2,
    const short* __restrict__ Vt1, const short* __restrict__ Vt2,
    short* __restrict__ Ocat) {
  __shared__ short K1s[2][4096], K2s[2][4096], V1s[2][4096], V2s[2][4096];
  __shared__ short Ps[4][1024];  // per wave: 16 q-rows x 64 kv bf16, swizzled

  const int tid = threadIdx.x;
  const int w = tid >> 6, l = tid & 63;
  const int qb = blockIdx.x, bh = blockIdx.y;
  const int b = bh >> 3, h = bh & 7;
  const int lrow = l & 15, g4 = l >> 4, lk8 = g4 * 8;

  const short* Q1p = QK1 + (size_t)b * 2048 * 1024 + h * 64;
  const short* K1p = Q1p + 512;
  const short* Q2p = QK2 + (size_t)b * 2048 * 1024 + h * 64;
  const short* K2p = Q2p + 512;
  const short* V1p = Vt1 + (size_t)bh * 64 * 2048;
  const short* V2p = Vt2 + (size_t)bh * 64 * 2048;
  short* PsW = &Ps[w][0];

  // Q fragments (B-operand: lane holds Q[q=lrow][d-chunk g4]) in registers
  const int qrow = qb * 64 + w * 16 + lrow;
  bf16x8 q1f[2], q2f[2];
  q1f[0] = *(const bf16x8*)&Q1p[(size_t)qrow * 1024 + lk8];
  q1f[1] = *(const bf16x8*)&Q1p[(size_t)qrow * 1024 + 32 + lk8];
  q2f[0] = *(const bf16x8*)&Q2p[(size_t)qrow * 1024 + lk8];
  q2f[1] = *(const bf16x8*)&Q2p[(size_t)qrow * 1024 + 32 + lk8];

  // O^T accumulators: o[nf][r] = O[d=nf*16+g4*4+r][q=lrow]
  f32x4 o1[4] = {}, o2[4] = {};
  float mrun = -1e30f, lrun = 0.f;

  auto stage = [&](int buf, int kt) {
    const int kv0 = kt * 64;
    for (int g = 0; g < 2; ++g) {
      int cl = g * 256 + w * 64 + l;  // LDS 16B-chunk index, linear
      int row = cl >> 3;
      int lc = (cl & 7) ^ (row & 7);  // pre-swizzled global chunk
      int ldsoff = cl * 8;
      gld_lds16(K1p + (size_t)(kv0 + row) * 1024 + lc * 8, (void*)(&K1s[buf][ldsoff]));
      gld_lds16(K2p + (size_t)(kv0 + row) * 1024 + lc * 8, (void*)(&K2s[buf][ldsoff]));
      gld_lds16(V1p + (size_t)row * 2048 + kv0 + lc * 8, (void*)(&V1s[buf][ldsoff]));
      gld_lds16(V2p + (size_t)row * 2048 + kv0 + lc * 8, (void*)(&V2s[buf][ldsoff]));
    }
  };
  auto sw = [&](int row, int kc) { return row * 64 + ((kc ^ (row & 7)) * 8); };

  int cur = 0;
  stage(0, 0);
  __syncthreads();

  for (int kt = 0; kt < 32; ++kt) {
    if (kt + 1 < 32) stage(cur ^ 1, kt + 1);  // prefetch overlaps compute

    // S^T: s[nf][r] = SCALE*(Q1K1^T + Q2K2^T)[q=lrow][kv=nf*16+g4*4+r]
    f32x4 s[4] = {};
    __builtin_amdgcn_s_setprio(1);
#pragma unroll
    for (int nf = 0; nf < 4; ++nf) {
      int row = nf * 16 + lrow;
      bf16x8 k1a = *(const bf16x8*)&K1s[cur][sw(row, g4)];
      bf16x8 k1b = *(const bf16x8*)&K1s[cur][sw(row, 4 + g4)];
      bf16x8 k2a = *(const bf16x8*)&K2s[cur][sw(row, g4)];
      bf16x8 k2b = *(const bf16x8*)&K2s[cur][sw(row, 4 + g4)];
      s[nf] = MFMA(k1a, q1f[0], s[nf]);
      s[nf] = MFMA(k1b, q1f[1], s[nf]);
      s[nf] = MFMA(k2a, q2f[0], s[nf]);
      s[nf] = MFMA(k2b, q2f[1], s[nf]);
    }
    __builtin_amdgcn_s_setprio(0);

    // in-register online softmax for q-row lrow (replicated over g4 groups)
    float t[16];
#pragma unroll
    for (int nf = 0; nf < 4; ++nf)
#pragma unroll
      for (int r = 0; r < 4; ++r) t[nf * 4 + r] = s[nf][r] * SCALE_F;
    float mx = t[0];
#pragma unroll
    for (int i = 1; i < 16; ++i) mx = fmaxf(mx, t[i]);
    mx = fmaxf(mx, __shfl_xor(mx, 16));
    mx = fmaxf(mx, __shfl_xor(mx, 32));
    if (!__all(mx - mrun <= 8.0f)) {  // defer-max: rescale rarely fires
      float newm = fmaxf(mrun, mx);
      float corr = __expf(mrun - newm);
      mrun = newm;
      lrun *= corr;
#pragma unroll
      for (int nf = 0; nf < 4; ++nf)
#pragma unroll
        for (int r = 0; r < 4; ++r) { o1[nf][r] *= corr; o2[nf][r] *= corr; }
    }
    float p[16];
    float ps = 0.f;
#pragma unroll
    for (int i = 0; i < 16; ++i) { p[i] = __expf(t[i] - mrun); ps += p[i]; }
    ps += __shfl_xor(ps, 16);
    ps += __shfl_xor(ps, 32);
    lrun += ps;

    // pack P -> bf16 and store to swizzled Ps (wave-private, no barrier)
#pragma unroll
    for (int nf = 0; nf < 4; ++nf) {
      s16x4 pv;
      pv.x = f2bf(p[nf * 4 + 0]);
      pv.y = f2bf(p[nf * 4 + 1]);
      pv.z = f2bf(p[nf * 4 + 2]);
      pv.w = f2bf(p[nf * 4 + 3]);
      int wi = lrow * 64 + (((2 * nf + (g4 >> 1)) ^ (lrow & 7)) << 3) +
               ((g4 & 1) << 2);
      *(s16x4*)&PsW[wi] = pv;
    }

    // P B-fragments: lane holds P[q=lrow][kv = 32*f + g4*8 + j]
    bf16x8 pb0 = *(const bf16x8*)&PsW[lrow * 64 + ((g4 ^ (lrow & 7)) << 3)];
    bf16x8 pb1 =
        *(const bf16x8*)&PsW[lrow * 64 + (((4 + g4) ^ (lrow & 7)) << 3)];

    // PV: O^T += V^T P^T
    __builtin_amdgcn_s_setprio(1);
#pragma unroll
    for (int nf = 0; nf < 4; ++nf) {
      int row = nf * 16 + lrow;
      bf16x8 v1a = *(const bf16x8*)&V1s[cur][sw(row, g4)];
      bf16x8 v1b = *(const bf16x8*)&V1s[cur][sw(row, 4 + g4)];
      bf16x8 v2a = *(const bf16x8*)&V2s[cur][sw(row, g4)];
      bf16x8 v2b = *(const bf16x8*)&V2s[cur][sw(row, 4 + g4)];
      o1[nf] = MFMA(v1a, pb0, o1[nf]);
      o1[nf] = MFMA(v1b, pb1, o1[nf]);
      o2[nf] = MFMA(v2a, pb0, o2[nf]);
      o2[nf] = MFMA(v2b, pb1, o2[nf]);
    }
    __builtin_amdgcn_s_setprio(0);

    __syncthreads();  // next tile staged AND everyone done with cur
    cur ^= 1;
  }

  // epilogue: normalize (per q-row = per lane) and write [b, n, h*64+d]
  float inv = 1.0f / lrun;
  const size_t base1 = ((size_t)b * 4096 + qrow) * 512 + h * 64;
  const size_t base2 = base1 + (size_t)2048 * 512;
#pragma unroll
  for (int nf = 0; nf < 4; ++nf) {
    int d0 = nf * 16 + g4 * 4;
    s16x4 ov;
    ov.x = f2bf(o1[nf][0] * inv);
    ov.y = f2bf(o1[nf][1] * inv);
    ov.z = f2bf(o1[nf][2] * inv);
    ov.w = f2bf(o1[nf][3] * inv);
    *(s16x4*)&Ocat[base1 + d0] = ov;
    ov.x = f2bf(o2[nf][0] * inv);
    ov.y = f2bf(o2[nf][1] * inv);
    ov.z = f2bf(o2[nf][2] * inv);
    ov.w = f2bf(o2[nf][3] * inv);
    *(s16x4*)&Ocat[base2 + d0] = ov;
  }
}

// ---------------------------------------------------------------------------
extern "C" void kernel_launch(void* const* d_in, const int* in_sizes, int n_in,
                              void* d_out, int out_size, void* d_ws,
                              size_t ws_size, hipStream_t stream) {
  const float* x1 = (const float*)d_in[0];
  const float* x2 = (const float*)d_in[1];
  const float* Wq1 = (const float*)d_in[2];
  const float* Wq2 = (const float*)d_in[3];
  const float* Wo = (const float*)d_in[4];
  const float* bo = (const float*)d_in[5];
  float* out = (float*)d_out;

  // workspace layout (bf16 elements); total ~45.6 MB
  short* p = (short*)d_ws;
  short* xb1 = p;  p += (size_t)4096 * 512;
  short* xb2 = p;  p += (size_t)4096 * 512;
  short* W1t = p;  p += (size_t)1536 * 512;
  short* W2t = p;  p += (size_t)1536 * 512;
  short* Wot = p;  p += (size_t)512 * 512;
  short* QK1 = p;  p += (size_t)4096 * 1024;
  short* QK2 = p;  p += (size_t)4096 * 1024;
  short* Vt1 = p;  p += (size_t)2 * 8 * 64 * 2048;
  short* Vt2 = p;  p += (size_t)2 * 8 * 64 * 2048;
  short* Ocat = p; p += (size_t)8192 * 512;

  cast_bf16_dual<<<4096, 256, 0, stream>>>(x1, x2, xb1, xb2, 4096 * 512);
  cast_transpose_dual<<<(2 * 512 * 1536 + 255) / 256, 256, 0, stream>>>(
      Wq1, Wq2, W1t, W2t, 512, 1536);
  cast_transpose_kernel<<<(512 * 512 + 255) / 256, 256, 0, stream>>>(Wo, Wot,
                                                                     512, 512);

  gemm_qkv<<<dim3(32, 24), 256, 0, stream>>>(xb1, xb2, W1t, W2t, QK1, QK2,
                                             Vt1, Vt2);

  attn_kernel<<<dim3(32, 16), 256, 0, stream>>>(QK1, QK2, Vt1, Vt2, Ocat);

  gemm_out<<<dim3(64, 4), 256, 0, stream>>>(Ocat, Wot, 8192, 512, 512, out,
                                            bo);
}

// Round 5
// 130.982 us; speedup vs baseline: 1.5384x; 1.0000x over previous
//
#include <hip/hip_runtime.h>
#include <hip/hip_bf16.h>

typedef __attribute__((ext_vector_type(8))) short bf16x8;
typedef __attribute__((ext_vector_type(4))) float f32x4;
typedef __attribute__((ext_vector_type(4))) short s16x4;

#define MFMA(a, b, c) __builtin_amdgcn_mfma_f32_16x16x32_bf16(a, b, c, 0, 0, 0)

#define SCALE_F 0.08838834764831845f  // (2*64)^-0.5

__device__ __forceinline__ short f2bf(float f) {
  __hip_bfloat16 h = __float2bfloat16(f);
  return *reinterpret_cast<short*>(&h);
}

__device__ __forceinline__ void gld_lds16(const void* g, void* s) {
  __builtin_amdgcn_global_load_lds(
      (const __attribute__((address_space(1))) void*)g,
      (__attribute__((address_space(3))) void*)s, 16, 0, 0);
}

// ---------------------------------------------------------------------------
// cast fp32 -> bf16, two tensors in one launch
__global__ void cast_bf16_dual(const float* __restrict__ a,
                               const float* __restrict__ b,
                               short* __restrict__ oa, short* __restrict__ ob,
                               int n) {
  int idx = (blockIdx.x * 256 + threadIdx.x) * 4;
  const float* src = a;
  short* dst = oa;
  if (idx >= n) { idx -= n; src = b; dst = ob; }
  float4 v = *(const float4*)&src[idx];
  s16x4 o;
  o.x = f2bf(v.x); o.y = f2bf(v.y); o.z = f2bf(v.z); o.w = f2bf(v.w);
  *(s16x4*)&dst[idx] = o;
}

// cast fp32 [R][C] -> bf16 [C][R], two tensors in one launch
__global__ void cast_transpose_dual(const float* __restrict__ a,
                                    const float* __restrict__ b,
                                    short* __restrict__ oa,
                                    short* __restrict__ ob, int R, int C) {
  int i = blockIdx.x * 256 + threadIdx.x;
  const float* src = a;
  short* dst = oa;
  if (i >= R * C) { i -= R * C; src = b; dst = ob; }
  int r = i / C, c = i % C;
  dst[(size_t)c * R + r] = f2bf(src[i]);
}

__global__ void cast_transpose_kernel(const float* __restrict__ in,
                                      short* __restrict__ out, int R, int C) {
  int i = blockIdx.x * 256 + threadIdx.x;
  if (i < R * C) {
    int r = i / C, c = i % C;
    out[(size_t)c * R + r] = f2bf(in[i]);
  }
}

// ---------------------------------------------------------------------------
// Merged dual-stream QKV GEMM: C = x @ Wqkv for both streams in one launch.
// grid (32, 24): blockIdx.y < 12 -> stream 1, else stream 2.
__global__ __launch_bounds__(256) void gemm_qkv(
    const short* __restrict__ xb1, const short* __restrict__ xb2,
    const short* __restrict__ W1t, const short* __restrict__ W2t,
    short* __restrict__ QK1, short* __restrict__ QK2,
    short* __restrict__ Vt1, short* __restrict__ Vt2) {
  __shared__ short As[128 * 64];
  __shared__ short Bs[128 * 64];
  const int tid = threadIdx.x;
  const int w = tid >> 6, l = tid & 63;
  const int sid = blockIdx.y >= 12;
  const short* A = sid ? xb2 : xb1;
  const short* Bt = sid ? W2t : W1t;
  short* C0 = sid ? QK2 : QK1;
  short* C1 = sid ? Vt2 : Vt1;
  const int m0 = blockIdx.x * 128;
  const int n0 = (sid ? blockIdx.y - 12 : blockIdx.y) * 128;
  const int mi = (w >> 1) * 64, ni = (w & 1) * 64;
  const int lrow = l & 15, lk8 = (l >> 4) * 8;
  const int K = 512;

  f32x4 acc[4][4] = {};

  for (int k0 = 0; k0 < K; k0 += 64) {
    for (int g = 0; g < 4; ++g) {
      int c = g * 256 + w * 64 + l;
      int row = c >> 3, c8 = (c & 7) * 8;
      int ldsoff = (g * 256 + w * 64) * 8;
      gld_lds16(A + (size_t)(m0 + row) * K + k0 + c8, (void*)(As + ldsoff));
      gld_lds16(Bt + (size_t)(n0 + row) * K + k0 + c8, (void*)(Bs + ldsoff));
    }
    __syncthreads();
    __builtin_amdgcn_s_setprio(1);
    for (int kp = 0; kp < 2; ++kp) {
      bf16x8 af[4], bfr[4];
      for (int mf = 0; mf < 4; ++mf)
        af[mf] = *(const bf16x8*)&As[(mi + mf * 16 + lrow) * 64 + kp * 32 + lk8];
      for (int nf = 0; nf < 4; ++nf)
        bfr[nf] = *(const bf16x8*)&Bs[(ni + nf * 16 + lrow) * 64 + kp * 32 + lk8];
      for (int mf = 0; mf < 4; ++mf)
        for (int nf = 0; nf < 4; ++nf)
          acc[mf][nf] = MFMA(af[mf], bfr[nf], acc[mf][nf]);
    }
    __builtin_amdgcn_s_setprio(0);
    __syncthreads();
  }

  for (int mf = 0; mf < 4; ++mf)
    for (int nf = 0; nf < 4; ++nf)
      for (int r = 0; r < 4; ++r) {
        int row = m0 + mi + mf * 16 + (l >> 4) * 4 + r;
        int col = n0 + ni + nf * 16 + lrow;
        float v = acc[mf][nf][r];
        if (col < 1024) {
          C0[(size_t)row * 1024 + col] = f2bf(v);
        } else {
          int b = row >> 11, n = row & 2047;
          int cv = col - 1024, h = cv >> 6, d = cv & 63;
          C1[(((size_t)(b * 8 + h) * 64 + d) << 11) + n] = f2bf(v);
        }
      }
}

// ---------------------------------------------------------------------------
// Output-projection GEMM: Cf[M,N] = A[M,K] @ Wot[N,K]^T + bias
__global__ __launch_bounds__(256) void gemm_out(
    const short* __restrict__ A, const short* __restrict__ Bt, int M, int N,
    int K, float* __restrict__ Cf, const float* __restrict__ bias) {
  __shared__ short As[128 * 64];
  __shared__ short Bs[128 * 64];
  const int tid = threadIdx.x;
  const int w = tid >> 6, l = tid & 63;
  const int m0 = blockIdx.x * 128, n0 = blockIdx.y * 128;
  const int mi = (w >> 1) * 64, ni = (w & 1) * 64;
  const int lrow = l & 15, lk8 = (l >> 4) * 8;

  f32x4 acc[4][4] = {};

  for (int k0 = 0; k0 < K; k0 += 64) {
    for (int g = 0; g < 4; ++g) {
      int c = g * 256 + w * 64 + l;
      int row = c >> 3, c8 = (c & 7) * 8;
      int ldsoff = (g * 256 + w * 64) * 8;
      gld_lds16(A + (size_t)(m0 + row) * K + k0 + c8, (void*)(As + ldsoff));
      gld_lds16(Bt + (size_t)(n0 + row) * K + k0 + c8, (void*)(Bs + ldsoff));
    }
    __syncthreads();
    __builtin_amdgcn_s_setprio(1);
    for (int kp = 0; kp < 2; ++kp) {
      bf16x8 af[4], bfr[4];
      for (int mf = 0; mf < 4; ++mf)
        af[mf] = *(const bf16x8*)&As[(mi + mf * 16 + lrow) * 64 + kp * 32 + lk8];
      for (int nf = 0; nf < 4; ++nf)
        bfr[nf] = *(const bf16x8*)&Bs[(ni + nf * 16 + lrow) * 64 + kp * 32 + lk8];
      for (int mf = 0; mf < 4; ++mf)
        for (int nf = 0; nf < 4; ++nf)
          acc[mf][nf] = MFMA(af[mf], bfr[nf], acc[mf][nf]);
    }
    __builtin_amdgcn_s_setprio(0);
    __syncthreads();
  }

  for (int mf = 0; mf < 4; ++mf)
    for (int nf = 0; nf < 4; ++nf)
      for (int r = 0; r < 4; ++r) {
        int row = m0 + mi + mf * 16 + (l >> 4) * 4 + r;
        int col = n0 + ni + nf * 16 + lrow;
        Cf[(size_t)row * N + col] = acc[mf][nf][r] + bias[col];
      }
}

// ---------------------------------------------------------------------------
// Dual-stream flash attention, v4: counted-vmcnt pipeline (T3/T4).
// Per iter: stage(t+1) -> vmcnt(8) [t's loads done, t+1 stays in flight]
// -> s_barrier -> compute -> lgkmcnt(0) -> s_barrier. The t+1 prefetch is
// never drained at a barrier (m201 pattern), unlike __syncthreads' vmcnt(0).
__global__ __launch_bounds__(256) void attn_kernel(
    const short* __restrict__ QK1, const short* __restrict__ QK2,
    const short* __restrict__ Vt1, const short* __restrict__ Vt2,
    short* __restrict__ Ocat) {
  __shared__ short K1s[2][4096], K2s[2][4096], V1s[2][4096], V2s[2][4096];
  __shared__ short Ps[4][1024];  // per wave: 16 q-rows x 64 kv bf16, swizzled

  const int tid = threadIdx.x;
  const int w = tid >> 6, l = tid & 63;
  const int qb = blockIdx.x, bh = blockIdx.y;
  const int b = bh >> 3, h = bh & 7;
  const int lrow = l & 15, g4 = l >> 4, lk8 = g4 * 8;

  const short* Q1p = QK1 + (size_t)b * 2048 * 1024 + h * 64;
  const short* K1p = Q1p + 512;
  const short* Q2p = QK2 + (size_t)b * 2048 * 1024 + h * 64;
  const short* K2p = Q2p + 512;
  const short* V1p = Vt1 + (size_t)bh * 64 * 2048;
  const short* V2p = Vt2 + (size_t)bh * 64 * 2048;
  short* PsW = &Ps[w][0];

  // Q fragments (B-operand: lane holds Q[q=lrow][d-chunk g4]) in registers
  const int qrow = qb * 64 + w * 16 + lrow;
  bf16x8 q1f[2], q2f[2];
  q1f[0] = *(const bf16x8*)&Q1p[(size_t)qrow * 1024 + lk8];
  q1f[1] = *(const bf16x8*)&Q1p[(size_t)qrow * 1024 + 32 + lk8];
  q2f[0] = *(const bf16x8*)&Q2p[(size_t)qrow * 1024 + lk8];
  q2f[1] = *(const bf16x8*)&Q2p[(size_t)qrow * 1024 + 32 + lk8];

  // O^T accumulators: o[nf][r] = O[d=nf*16+g4*4+r][q=lrow]
  f32x4 o1[4] = {}, o2[4] = {};
  float mrun = -1e30f, lrun = 0.f;

  auto stage = [&](int buf, int kt) {
    const int kv0 = kt * 64;
    for (int g = 0; g < 2; ++g) {
      int cl = g * 256 + w * 64 + l;  // LDS 16B-chunk index, linear
      int row = cl >> 3;
      int lc = (cl & 7) ^ (row & 7);  // pre-swizzled global chunk
      int ldsoff = cl * 8;
      gld_lds16(K1p + (size_t)(kv0 + row) * 1024 + lc * 8, (void*)(&K1s[buf][ldsoff]));
      gld_lds16(K2p + (size_t)(kv0 + row) * 1024 + lc * 8, (void*)(&K2s[buf][ldsoff]));
      gld_lds16(V1p + (size_t)row * 2048 + kv0 + lc * 8, (void*)(&V1s[buf][ldsoff]));
      gld_lds16(V2p + (size_t)row * 2048 + kv0 + lc * 8, (void*)(&V2s[buf][ldsoff]));
    }
  };
  auto sw = [&](int row, int kc) { return row * 64 + ((kc ^ (row & 7)) * 8); };

  int cur = 0;
  stage(0, 0);

  for (int kt = 0; kt < 32; ++kt) {
    if (kt + 1 < 32) {
      stage(cur ^ 1, kt + 1);  // 8 loads in flight across the whole iter
      asm volatile("s_waitcnt vmcnt(8)" ::: "memory");  // tile t complete
    } else {
      asm volatile("s_waitcnt vmcnt(0)" ::: "memory");  // last tile: drain
    }
    __builtin_amdgcn_s_barrier();  // tile t published to all waves

    // S^T: s[nf][r] = SCALE*(Q1K1^T + Q2K2^T)[q=lrow][kv=nf*16+g4*4+r]
    f32x4 s[4] = {};
    __builtin_amdgcn_s_setprio(1);
#pragma unroll
    for (int nf = 0; nf < 4; ++nf) {
      int row = nf * 16 + lrow;
      bf16x8 k1a = *(const bf16x8*)&K1s[cur][sw(row, g4)];
      bf16x8 k1b = *(const bf16x8*)&K1s[cur][sw(row, 4 + g4)];
      bf16x8 k2a = *(const bf16x8*)&K2s[cur][sw(row, g4)];
      bf16x8 k2b = *(const bf16x8*)&K2s[cur][sw(row, 4 + g4)];
      s[nf] = MFMA(k1a, q1f[0], s[nf]);
      s[nf] = MFMA(k1b, q1f[1], s[nf]);
      s[nf] = MFMA(k2a, q2f[0], s[nf]);
      s[nf] = MFMA(k2b, q2f[1], s[nf]);
    }
    __builtin_amdgcn_s_setprio(0);

    // in-register online softmax for q-row lrow (replicated over g4 groups)
    float t[16];
#pragma unroll
    for (int nf = 0; nf < 4; ++nf)
#pragma unroll
      for (int r = 0; r < 4; ++r) t[nf * 4 + r] = s[nf][r] * SCALE_F;
    float mx = t[0];
#pragma unroll
    for (int i = 1; i < 16; ++i) mx = fmaxf(mx, t[i]);
    mx = fmaxf(mx, __shfl_xor(mx, 16));
    mx = fmaxf(mx, __shfl_xor(mx, 32));
    if (!__all(mx - mrun <= 8.0f)) {  // defer-max: rescale rarely fires
      float newm = fmaxf(mrun, mx);
      float corr = __expf(mrun - newm);
      mrun = newm;
      lrun *= corr;
#pragma unroll
      for (int nf = 0; nf < 4; ++nf)
#pragma unroll
        for (int r = 0; r < 4; ++r) { o1[nf][r] *= corr; o2[nf][r] *= corr; }
    }
    float p[16];
    float ps = 0.f;
#pragma unroll
    for (int i = 0; i < 16; ++i) { p[i] = __expf(t[i] - mrun); ps += p[i]; }
    ps += __shfl_xor(ps, 16);
    ps += __shfl_xor(ps, 32);
    lrun += ps;

    // pack P -> bf16 and store to swizzled Ps (wave-private, no barrier)
#pragma unroll
    for (int nf = 0; nf < 4; ++nf) {
      s16x4 pv;
      pv.x = f2bf(p[nf * 4 + 0]);
      pv.y = f2bf(p[nf * 4 + 1]);
      pv.z = f2bf(p[nf * 4 + 2]);
      pv.w = f2bf(p[nf * 4 + 3]);
      int wi = lrow * 64 + (((2 * nf + (g4 >> 1)) ^ (lrow & 7)) << 3) +
               ((g4 & 1) << 2);
      *(s16x4*)&PsW[wi] = pv;
    }

    // P B-fragments: lane holds P[q=lrow][kv = 32*f + g4*8 + j]
    bf16x8 pb0 = *(const bf16x8*)&PsW[lrow * 64 + ((g4 ^ (lrow & 7)) << 3)];
    bf16x8 pb1 =
        *(const bf16x8*)&PsW[lrow * 64 + (((4 + g4) ^ (lrow & 7)) << 3)];

    // PV: O^T += V^T P^T
    __builtin_amdgcn_s_setprio(1);
#pragma unroll
    for (int nf = 0; nf < 4; ++nf) {
      int row = nf * 16 + lrow;
      bf16x8 v1a = *(const bf16x8*)&V1s[cur][sw(row, g4)];
      bf16x8 v1b = *(const bf16x8*)&V1s[cur][sw(row, 4 + g4)];
      bf16x8 v2a = *(const bf16x8*)&V2s[cur][sw(row, g4)];
      bf16x8 v2b = *(const bf16x8*)&V2s[cur][sw(row, 4 + g4)];
      o1[nf] = MFMA(v1a, pb0, o1[nf]);
      o1[nf] = MFMA(v1b, pb1, o1[nf]);
      o2[nf] = MFMA(v2a, pb0, o2[nf]);
      o2[nf] = MFMA(v2b, pb1, o2[nf]);
    }
    __builtin_amdgcn_s_setprio(0);

    // all my LDS reads of buf `cur` done -> publish, then next iter may
    // overwrite it with stage(t+2)
    asm volatile("s_waitcnt lgkmcnt(0)" ::: "memory");
    __builtin_amdgcn_s_barrier();
    cur ^= 1;
  }

  // epilogue: normalize (per q-row = per lane) and write [b, n, h*64+d]
  float inv = 1.0f / lrun;
  const size_t base1 = ((size_t)b * 4096 + qrow) * 512 + h * 64;
  const size_t base2 = base1 + (size_t)2048 * 512;
#pragma unroll
  for (int nf = 0; nf < 4; ++nf) {
    int d0 = nf * 16 + g4 * 4;
    s16x4 ov;
    ov.x = f2bf(o1[nf][0] * inv);
    ov.y = f2bf(o1[nf][1] * inv);
    ov.z = f2bf(o1[nf][2] * inv);
    ov.w = f2bf(o1[nf][3] * inv);
    *(s16x4*)&Ocat[base1 + d0] = ov;
    ov.x = f2bf(o2[nf][0] * inv);
    ov.y = f2bf(o2[nf][1] * inv);
    ov.z = f2bf(o2[nf][2] * inv);
    ov.w = f2bf(o2[nf][3] * inv);
    *(s16x4*)&Ocat[base2 + d0] = ov;
  }
}

// ---------------------------------------------------------------------------
extern "C" void kernel_launch(void* const* d_in, const int* in_sizes, int n_in,
                              void* d_out, int out_size, void* d_ws,
                              size_t ws_size, hipStream_t stream) {
  const float* x1 = (const float*)d_in[0];
  const float* x2 = (const float*)d_in[1];
  const float* Wq1 = (const float*)d_in[2];
  const float* Wq2 = (const float*)d_in[3];
  const float* Wo = (const float*)d_in[4];
  const float* bo = (const float*)d_in[5];
  float* out = (float*)d_out;

  // workspace layout (bf16 elements); total ~45.6 MB
  short* p = (short*)d_ws;
  short* xb1 = p;  p += (size_t)4096 * 512;
  short* xb2 = p;  p += (size_t)4096 * 512;
  short* W1t = p;  p += (size_t)1536 * 512;
  short* W2t = p;  p += (size_t)1536 * 512;
  short* Wot = p;  p += (size_t)512 * 512;
  short* QK1 = p;  p += (size_t)4096 * 1024;
  short* QK2 = p;  p += (size_t)4096 * 1024;
  short* Vt1 = p;  p += (size_t)2 * 8 * 64 * 2048;
  short* Vt2 = p;  p += (size_t)2 * 8 * 64 * 2048;
  short* Ocat = p; p += (size_t)8192 * 512;

  cast_bf16_dual<<<4096, 256, 0, stream>>>(x1, x2, xb1, xb2, 4096 * 512);
  cast_transpose_dual<<<(2 * 512 * 1536 + 255) / 256, 256, 0, stream>>>(
      Wq1, Wq2, W1t, W2t, 512, 1536);
  cast_transpose_kernel<<<(512 * 512 + 255) / 256, 256, 0, stream>>>(Wo, Wot,
                                                                     512, 512);

  gemm_qkv<<<dim3(32, 24), 256, 0, stream>>>(xb1, xb2, W1t, W2t, QK1, QK2,
                                             Vt1, Vt2);

  attn_kernel<<<dim3(32, 16), 256, 0, stream>>>(QK1, QK2, Vt1, Vt2, Ocat);

  gemm_out<<<dim3(64, 4), 256, 0, stream>>>(Ocat, Wot, 8192, 512, 512, out,
                                            bo);
}

// Round 6
// 120.534 us; speedup vs baseline: 1.6718x; 1.0867x over previous
//
#include <hip/hip_runtime.h>
#include <hip/hip_bf16.h>

typedef __attribute__((ext_vector_type(8))) short bf16x8;
typedef __attribute__((ext_vector_type(4))) float f32x4;
typedef __attribute__((ext_vector_type(4))) short s16x4;

#define MFMA(a, b, c) __builtin_amdgcn_mfma_f32_16x16x32_bf16(a, b, c, 0, 0, 0)

#define SCALE_F 0.08838834764831845f  // (2*64)^-0.5

__device__ __forceinline__ short f2bf(float f) {
  __hip_bfloat16 h = __float2bfloat16(f);
  return *reinterpret_cast<short*>(&h);
}

__device__ __forceinline__ void gld_lds16(const void* g, void* s) {
  __builtin_amdgcn_global_load_lds(
      (const __attribute__((address_space(1))) void*)g,
      (__attribute__((address_space(3))) void*)s, 16, 0, 0);
}

// ---------------------------------------------------------------------------
// cast fp32 -> bf16, two tensors in one launch
__global__ void cast_bf16_dual(const float* __restrict__ a,
                               const float* __restrict__ b,
                               short* __restrict__ oa, short* __restrict__ ob,
                               int n) {
  int idx = (blockIdx.x * 256 + threadIdx.x) * 4;
  const float* src = a;
  short* dst = oa;
  if (idx >= n) { idx -= n; src = b; dst = ob; }
  float4 v = *(const float4*)&src[idx];
  s16x4 o;
  o.x = f2bf(v.x); o.y = f2bf(v.y); o.z = f2bf(v.z); o.w = f2bf(v.w);
  *(s16x4*)&dst[idx] = o;
}

// cast fp32 [R][C] -> bf16 [C][R] for the QKV weights; Q-columns (c<512)
// pre-scaled by SCALE so the attention kernel never multiplies by SCALE.
__global__ void cast_transpose_dual(const float* __restrict__ a,
                                    const float* __restrict__ b,
                                    short* __restrict__ oa,
                                    short* __restrict__ ob, int R, int C) {
  int i = blockIdx.x * 256 + threadIdx.x;
  const float* src = a;
  short* dst = oa;
  if (i >= R * C) { i -= R * C; src = b; dst = ob; }
  int r = i / C, c = i % C;
  float v = src[i];
  if (c < 512) v *= SCALE_F;  // Q block of W_qkv
  dst[(size_t)c * R + r] = f2bf(v);
}

__global__ void cast_transpose_kernel(const float* __restrict__ in,
                                      short* __restrict__ out, int R, int C) {
  int i = blockIdx.x * 256 + threadIdx.x;
  if (i < R * C) {
    int r = i / C, c = i % C;
    out[(size_t)c * R + r] = f2bf(in[i]);
  }
}

// ---------------------------------------------------------------------------
// Merged dual-stream QKV GEMM: C = x @ Wqkv for both streams in one launch.
// grid (32, 24): blockIdx.y < 12 -> stream 1, else stream 2.
__global__ __launch_bounds__(256) void gemm_qkv(
    const short* __restrict__ xb1, const short* __restrict__ xb2,
    const short* __restrict__ W1t, const short* __restrict__ W2t,
    short* __restrict__ QK1, short* __restrict__ QK2,
    short* __restrict__ Vt1, short* __restrict__ Vt2) {
  __shared__ short As[128 * 64];
  __shared__ short Bs[128 * 64];
  const int tid = threadIdx.x;
  const int w = tid >> 6, l = tid & 63;
  const int sid = blockIdx.y >= 12;
  const short* A = sid ? xb2 : xb1;
  const short* Bt = sid ? W2t : W1t;
  short* C0 = sid ? QK2 : QK1;
  short* C1 = sid ? Vt2 : Vt1;
  const int m0 = blockIdx.x * 128;
  const int n0 = (sid ? blockIdx.y - 12 : blockIdx.y) * 128;
  const int mi = (w >> 1) * 64, ni = (w & 1) * 64;
  const int lrow = l & 15, lk8 = (l >> 4) * 8;
  const int K = 512;

  f32x4 acc[4][4] = {};

  for (int k0 = 0; k0 < K; k0 += 64) {
    for (int g = 0; g < 4; ++g) {
      int c = g * 256 + w * 64 + l;
      int row = c >> 3, c8 = (c & 7) * 8;
      int ldsoff = (g * 256 + w * 64) * 8;
      gld_lds16(A + (size_t)(m0 + row) * K + k0 + c8, (void*)(As + ldsoff));
      gld_lds16(Bt + (size_t)(n0 + row) * K + k0 + c8, (void*)(Bs + ldsoff));
    }
    __syncthreads();
    __builtin_amdgcn_s_setprio(1);
    for (int kp = 0; kp < 2; ++kp) {
      bf16x8 af[4], bfr[4];
      for (int mf = 0; mf < 4; ++mf)
        af[mf] = *(const bf16x8*)&As[(mi + mf * 16 + lrow) * 64 + kp * 32 + lk8];
      for (int nf = 0; nf < 4; ++nf)
        bfr[nf] = *(const bf16x8*)&Bs[(ni + nf * 16 + lrow) * 64 + kp * 32 + lk8];
      for (int mf = 0; mf < 4; ++mf)
        for (int nf = 0; nf < 4; ++nf)
          acc[mf][nf] = MFMA(af[mf], bfr[nf], acc[mf][nf]);
    }
    __builtin_amdgcn_s_setprio(0);
    __syncthreads();
  }

  for (int mf = 0; mf < 4; ++mf)
    for (int nf = 0; nf < 4; ++nf)
      for (int r = 0; r < 4; ++r) {
        int row = m0 + mi + mf * 16 + (l >> 4) * 4 + r;
        int col = n0 + ni + nf * 16 + lrow;
        float v = acc[mf][nf][r];
        if (col < 1024) {
          C0[(size_t)row * 1024 + col] = f2bf(v);
        } else {
          int b = row >> 11, n = row & 2047;
          int cv = col - 1024, h = cv >> 6, d = cv & 63;
          C1[(((size_t)(b * 8 + h) * 64 + d) << 11) + n] = f2bf(v);
        }
      }
}

// ---------------------------------------------------------------------------
// Output-projection GEMM: Cf[M,N] = A[M,K] @ Wot[N,K]^T + bias
__global__ __launch_bounds__(256) void gemm_out(
    const short* __restrict__ A, const short* __restrict__ Bt, int M, int N,
    int K, float* __restrict__ Cf, const float* __restrict__ bias) {
  __shared__ short As[128 * 64];
  __shared__ short Bs[128 * 64];
  const int tid = threadIdx.x;
  const int w = tid >> 6, l = tid & 63;
  const int m0 = blockIdx.x * 128, n0 = blockIdx.y * 128;
  const int mi = (w >> 1) * 64, ni = (w & 1) * 64;
  const int lrow = l & 15, lk8 = (l >> 4) * 8;

  f32x4 acc[4][4] = {};

  for (int k0 = 0; k0 < K; k0 += 64) {
    for (int g = 0; g < 4; ++g) {
      int c = g * 256 + w * 64 + l;
      int row = c >> 3, c8 = (c & 7) * 8;
      int ldsoff = (g * 256 + w * 64) * 8;
      gld_lds16(A + (size_t)(m0 + row) * K + k0 + c8, (void*)(As + ldsoff));
      gld_lds16(Bt + (size_t)(n0 + row) * K + k0 + c8, (void*)(Bs + ldsoff));
    }
    __syncthreads();
    __builtin_amdgcn_s_setprio(1);
    for (int kp = 0; kp < 2; ++kp) {
      bf16x8 af[4], bfr[4];
      for (int mf = 0; mf < 4; ++mf)
        af[mf] = *(const bf16x8*)&As[(mi + mf * 16 + lrow) * 64 + kp * 32 + lk8];
      for (int nf = 0; nf < 4; ++nf)
        bfr[nf] = *(const bf16x8*)&Bs[(ni + nf * 16 + lrow) * 64 + kp * 32 + lk8];
      for (int mf = 0; mf < 4; ++mf)
        for (int nf = 0; nf < 4; ++nf)
          acc[mf][nf] = MFMA(af[mf], bfr[nf], acc[mf][nf]);
    }
    __builtin_amdgcn_s_setprio(0);
    __syncthreads();
  }

  for (int mf = 0; mf < 4; ++mf)
    for (int nf = 0; nf < 4; ++nf)
      for (int r = 0; r < 4; ++r) {
        int row = m0 + mi + mf * 16 + (l >> 4) * 4 + r;
        int col = n0 + ni + nf * 16 + lrow;
        Cf[(size_t)row * N + col] = acc[mf][nf][r] + bias[col];
      }
}

// ---------------------------------------------------------------------------
// Dual-stream flash attention, v5: permuted-K staging makes the QK C-fragment
// land exactly in PV B-fragment lane layout -> P never leaves registers.
// K LDS row rho holds global K row pi(rho), pi = 32*((rho>>4)&1) +
// 8*((rho>>2)&3) + 4*(rho>>5) + (rho&3). Then lane (g4,lrow) owns
// kv in {8g4..8g4+7} u {32+8g4..+7}: pb0=[s0|s2], pb1=[s1|s3] directly.
// Softmax common path has ZERO cross-lane ops: __all() is the max reduce
// (full reduce only in the rare rescale branch); lrun is per-lane partial,
// reduced once in the epilogue. S arrives pre-scaled (SCALE folded into Wq).
__global__ __launch_bounds__(256) void attn_kernel(
    const short* __restrict__ QK1, const short* __restrict__ QK2,
    const short* __restrict__ Vt1, const short* __restrict__ Vt2,
    short* __restrict__ Ocat) {
  __shared__ short K1s[2][4096], K2s[2][4096], V1s[2][4096], V2s[2][4096];

  const int tid = threadIdx.x;
  const int w = tid >> 6, l = tid & 63;
  const int qb = blockIdx.x, bh = blockIdx.y;
  const int b = bh >> 3, h = bh & 7;
  const int lrow = l & 15, g4 = l >> 4, lk8 = g4 * 8;

  const short* Q1p = QK1 + (size_t)b * 2048 * 1024 + h * 64;
  const short* K1p = Q1p + 512;
  const short* Q2p = QK2 + (size_t)b * 2048 * 1024 + h * 64;
  const short* K2p = Q2p + 512;
  const short* V1p = Vt1 + (size_t)bh * 64 * 2048;
  const short* V2p = Vt2 + (size_t)bh * 64 * 2048;

  // Q fragments (B-operand: lane holds Q[q=lrow][d-chunk g4]) in registers
  const int qrow = qb * 64 + w * 16 + lrow;
  bf16x8 q1f[2], q2f[2];
  q1f[0] = *(const bf16x8*)&Q1p[(size_t)qrow * 1024 + lk8];
  q1f[1] = *(const bf16x8*)&Q1p[(size_t)qrow * 1024 + 32 + lk8];
  q2f[0] = *(const bf16x8*)&Q2p[(size_t)qrow * 1024 + lk8];
  q2f[1] = *(const bf16x8*)&Q2p[(size_t)qrow * 1024 + 32 + lk8];

  // O^T accumulators: o[nf][r] = O[d=nf*16+g4*4+r][q=lrow]
  f32x4 o1[4] = {}, o2[4] = {};
  float mrun = -1e30f, lrun = 0.f;

  auto stage = [&](int buf, int kt) {
    const int kv0 = kt * 64;
    for (int g = 0; g < 2; ++g) {
      int cl = g * 256 + w * 64 + l;  // LDS 16B-chunk index, linear
      int row = cl >> 3;
      int lc = (cl & 7) ^ (row & 7);  // bank-conflict XOR swizzle (rule 21)
      int ldsoff = cl * 8;
      // pi-permuted K row so QK output lands in PV lane layout
      int krow = kv0 + (((row >> 4) & 1) << 5) + ((row & 12) << 1) +
                 ((row >> 5) << 2) + (row & 3);
      gld_lds16(K1p + (size_t)krow * 1024 + lc * 8, (void*)(&K1s[buf][ldsoff]));
      gld_lds16(K2p + (size_t)krow * 1024 + lc * 8, (void*)(&K2s[buf][ldsoff]));
      gld_lds16(V1p + (size_t)row * 2048 + kv0 + lc * 8, (void*)(&V1s[buf][ldsoff]));
      gld_lds16(V2p + (size_t)row * 2048 + kv0 + lc * 8, (void*)(&V2s[buf][ldsoff]));
    }
  };
  auto sw = [&](int row, int kc) { return row * 64 + ((kc ^ (row & 7)) * 8); };

  int cur = 0;
  stage(0, 0);

  for (int kt = 0; kt < 32; ++kt) {
    if (kt + 1 < 32) {
      stage(cur ^ 1, kt + 1);  // 8 loads in flight across the whole iter
      asm volatile("s_waitcnt vmcnt(8)" ::: "memory");  // tile t complete
    } else {
      asm volatile("s_waitcnt vmcnt(0)" ::: "memory");  // last tile: drain
    }
    __builtin_amdgcn_s_barrier();  // tile t published to all waves

    // S^T (pre-scaled): lane (g4,lrow) gets kv = 32*(nf&1)+8*g4+4*(nf>>1)+r
    f32x4 s[4] = {};
    __builtin_amdgcn_s_setprio(1);
#pragma unroll
    for (int nf = 0; nf < 4; ++nf) {
      int row = nf * 16 + lrow;
      bf16x8 k1a = *(const bf16x8*)&K1s[cur][sw(row, g4)];
      bf16x8 k1b = *(const bf16x8*)&K1s[cur][sw(row, 4 + g4)];
      bf16x8 k2a = *(const bf16x8*)&K2s[cur][sw(row, g4)];
      bf16x8 k2b = *(const bf16x8*)&K2s[cur][sw(row, 4 + g4)];
      s[nf] = MFMA(k1a, q1f[0], s[nf]);
      s[nf] = MFMA(k1b, q1f[1], s[nf]);
      s[nf] = MFMA(k2a, q2f[0], s[nf]);
      s[nf] = MFMA(k2b, q2f[1], s[nf]);
    }
    __builtin_amdgcn_s_setprio(0);

    // online softmax, zero cross-lane ops in the common path
    float t[16];
#pragma unroll
    for (int nf = 0; nf < 4; ++nf)
#pragma unroll
      for (int r = 0; r < 4; ++r) t[nf * 4 + r] = s[nf][r];
    float mx = t[0];
#pragma unroll
    for (int i = 1; i < 16; ++i) mx = fmaxf(mx, t[i]);
    if (!__all(mx - mrun <= 8.0f)) {  // wave-AND doubles as the max reduce
      float rm = fmaxf(mx, __shfl_xor(mx, 16));
      rm = fmaxf(rm, __shfl_xor(rm, 32));
      float newm = fmaxf(mrun, rm);
      float corr = __expf(mrun - newm);
      mrun = newm;
      lrun *= corr;  // lrun is per-lane partial; corr is row-uniform
#pragma unroll
      for (int nf = 0; nf < 4; ++nf)
#pragma unroll
        for (int r = 0; r < 4; ++r) { o1[nf][r] *= corr; o2[nf][r] *= corr; }
    }
    float p[16];
#pragma unroll
    for (int i = 0; i < 16; ++i) { p[i] = __expf(t[i] - mrun); lrun += p[i]; }

    // P already lane-resident in PV B-layout: pb0=[s0|s2], pb1=[s1|s3]
    bf16x8 pb0, pb1;
#pragma unroll
    for (int j = 0; j < 4; ++j) {
      pb0[j] = f2bf(p[j]);
      pb0[4 + j] = f2bf(p[8 + j]);
      pb1[j] = f2bf(p[4 + j]);
      pb1[4 + j] = f2bf(p[12 + j]);
    }

    // PV: O^T += V^T P^T
    __builtin_amdgcn_s_setprio(1);
#pragma unroll
    for (int nf = 0; nf < 4; ++nf) {
      int row = nf * 16 + lrow;
      bf16x8 v1a = *(const bf16x8*)&V1s[cur][sw(row, g4)];
      bf16x8 v1b = *(const bf16x8*)&V1s[cur][sw(row, 4 + g4)];
      bf16x8 v2a = *(const bf16x8*)&V2s[cur][sw(row, g4)];
      bf16x8 v2b = *(const bf16x8*)&V2s[cur][sw(row, 4 + g4)];
      o1[nf] = MFMA(v1a, pb0, o1[nf]);
      o1[nf] = MFMA(v1b, pb1, o1[nf]);
      o2[nf] = MFMA(v2a, pb0, o2[nf]);
      o2[nf] = MFMA(v2b, pb1, o2[nf]);
    }
    __builtin_amdgcn_s_setprio(0);

    // all my LDS reads of buf `cur` done -> publish, then next iter may
    // overwrite it with stage(t+2)
    asm volatile("s_waitcnt lgkmcnt(0)" ::: "memory");
    __builtin_amdgcn_s_barrier();
    cur ^= 1;
  }

  // epilogue: reduce per-lane partial lrun across the 4 g4-lanes of the row
  lrun += __shfl_xor(lrun, 16);
  lrun += __shfl_xor(lrun, 32);
  float inv = 1.0f / lrun;
  const size_t base1 = ((size_t)b * 4096 + qrow) * 512 + h * 64;
  const size_t base2 = base1 + (size_t)2048 * 512;
#pragma unroll
  for (int nf = 0; nf < 4; ++nf) {
    int d0 = nf * 16 + g4 * 4;
    s16x4 ov;
    ov.x = f2bf(o1[nf][0] * inv);
    ov.y = f2bf(o1[nf][1] * inv);
    ov.z = f2bf(o1[nf][2] * inv);
    ov.w = f2bf(o1[nf][3] * inv);
    *(s16x4*)&Ocat[base1 + d0] = ov;
    ov.x = f2bf(o2[nf][0] * inv);
    ov.y = f2bf(o2[nf][1] * inv);
    ov.z = f2bf(o2[nf][2] * inv);
    ov.w = f2bf(o2[nf][3] * inv);
    *(s16x4*)&Ocat[base2 + d0] = ov;
  }
}

// ---------------------------------------------------------------------------
extern "C" void kernel_launch(void* const* d_in, const int* in_sizes, int n_in,
                              void* d_out, int out_size, void* d_ws,
                              size_t ws_size, hipStream_t stream) {
  const float* x1 = (const float*)d_in[0];
  const float* x2 = (const float*)d_in[1];
  const float* Wq1 = (const float*)d_in[2];
  const float* Wq2 = (const float*)d_in[3];
  const float* Wo = (const float*)d_in[4];
  const float* bo = (const float*)d_in[5];
  float* out = (float*)d_out;

  // workspace layout (bf16 elements); total ~45.6 MB
  short* p = (short*)d_ws;
  short* xb1 = p;  p += (size_t)4096 * 512;
  short* xb2 = p;  p += (size_t)4096 * 512;
  short* W1t = p;  p += (size_t)1536 * 512;
  short* W2t = p;  p += (size_t)1536 * 512;
  short* Wot = p;  p += (size_t)512 * 512;
  short* QK1 = p;  p += (size_t)4096 * 1024;
  short* QK2 = p;  p += (size_t)4096 * 1024;
  short* Vt1 = p;  p += (size_t)2 * 8 * 64 * 2048;
  short* Vt2 = p;  p += (size_t)2 * 8 * 64 * 2048;
  short* Ocat = p; p += (size_t)8192 * 512;

  cast_bf16_dual<<<4096, 256, 0, stream>>>(x1, x2, xb1, xb2, 4096 * 512);
  cast_transpose_dual<<<(2 * 512 * 1536 + 255) / 256, 256, 0, stream>>>(
      Wq1, Wq2, W1t, W2t, 512, 1536);
  cast_transpose_kernel<<<(512 * 512 + 255) / 256, 256, 0, stream>>>(Wo, Wot,
                                                                     512, 512);

  gemm_qkv<<<dim3(32, 24), 256, 0, stream>>>(xb1, xb2, W1t, W2t, QK1, QK2,
                                             Vt1, Vt2);

  attn_kernel<<<dim3(32, 16), 256, 0, stream>>>(QK1, QK2, Vt1, Vt2, Ocat);

  gemm_out<<<dim3(64, 4), 256, 0, stream>>>(Ocat, Wot, 8192, 512, 512, out,
                                            bo);
}

// Round 7
// 116.765 us; speedup vs baseline: 1.7258x; 1.0323x over previous
//
#include <hip/hip_runtime.h>
#include <hip/hip_bf16.h>

typedef __attribute__((ext_vector_type(8))) short bf16x8;
typedef __attribute__((ext_vector_type(4))) float f32x4;
typedef __attribute__((ext_vector_type(4))) short s16x4;
typedef __attribute__((ext_vector_type(4))) int i32x4;

#define MFMA(a, b, c) __builtin_amdgcn_mfma_f32_16x16x32_bf16(a, b, c, 0, 0, 0)

#define SCALE_F 0.08838834764831845f  // (2*64)^-0.5

__device__ __forceinline__ short f2bf(float f) {
  __hip_bfloat16 h = __float2bfloat16(f);
  return *reinterpret_cast<short*>(&h);
}

__device__ __forceinline__ void gld_lds16(const void* g, void* s) {
  __builtin_amdgcn_global_load_lds(
      (const __attribute__((address_space(1))) void*)g,
      (__attribute__((address_space(3))) void*)s, 16, 0, 0);
}

// ---------------------------------------------------------------------------
// cast fp32 -> bf16, two tensors in one launch
__global__ void cast_bf16_dual(const float* __restrict__ a,
                               const float* __restrict__ b,
                               short* __restrict__ oa, short* __restrict__ ob,
                               int n) {
  int idx = (blockIdx.x * 256 + threadIdx.x) * 4;
  const float* src = a;
  short* dst = oa;
  if (idx >= n) { idx -= n; src = b; dst = ob; }
  float4 v = *(const float4*)&src[idx];
  s16x4 o;
  o.x = f2bf(v.x); o.y = f2bf(v.y); o.z = f2bf(v.z); o.w = f2bf(v.w);
  *(s16x4*)&dst[idx] = o;
}

// merged transpose-cast of all three weights (R=512 for all):
// Wq1[512,1536]->W1t, Wq2->W2t (Q-cols pre-scaled), Wo[512,512]->Wot
__global__ void cast_transpose3(const float* __restrict__ Wq1,
                                const float* __restrict__ Wq2,
                                const float* __restrict__ Wo,
                                short* __restrict__ W1t,
                                short* __restrict__ W2t,
                                short* __restrict__ Wot) {
  int i = blockIdx.x * 256 + threadIdx.x;
  const float* src;
  short* dst;
  int C;
  if (i < 786432) {
    src = Wq1; dst = W1t; C = 1536;
  } else if (i < 1572864) {
    i -= 786432; src = Wq2; dst = W2t; C = 1536;
  } else {
    i -= 1572864;
    if (i >= 262144) return;
    src = Wo; dst = Wot; C = 512;
  }
  int r = i / C, c = i % C;
  float v = src[i];
  if (C == 1536 && c < 512) v *= SCALE_F;  // fold SCALE into Q block
  dst[(size_t)c * 512 + r] = f2bf(v);
}

// ---------------------------------------------------------------------------
// Merged dual-stream QKV GEMM: C = x @ Wqkv for both streams in one launch.
// grid (32, 24): blockIdx.y < 12 -> stream 1, else stream 2.
__global__ __launch_bounds__(256) void gemm_qkv(
    const short* __restrict__ xb1, const short* __restrict__ xb2,
    const short* __restrict__ W1t, const short* __restrict__ W2t,
    short* __restrict__ QK1, short* __restrict__ QK2,
    short* __restrict__ Vt1, short* __restrict__ Vt2) {
  __shared__ short As[128 * 64];
  __shared__ short Bs[128 * 64];
  const int tid = threadIdx.x;
  const int w = tid >> 6, l = tid & 63;
  const int sid = blockIdx.y >= 12;
  const short* A = sid ? xb2 : xb1;
  const short* Bt = sid ? W2t : W1t;
  short* C0 = sid ? QK2 : QK1;
  short* C1 = sid ? Vt2 : Vt1;
  const int m0 = blockIdx.x * 128;
  const int n0 = (sid ? blockIdx.y - 12 : blockIdx.y) * 128;
  const int mi = (w >> 1) * 64, ni = (w & 1) * 64;
  const int lrow = l & 15, lk8 = (l >> 4) * 8;
  const int K = 512;

  f32x4 acc[4][4] = {};

  for (int k0 = 0; k0 < K; k0 += 64) {
    for (int g = 0; g < 4; ++g) {
      int c = g * 256 + w * 64 + l;
      int row = c >> 3, c8 = (c & 7) * 8;
      int ldsoff = (g * 256 + w * 64) * 8;
      gld_lds16(A + (size_t)(m0 + row) * K + k0 + c8, (void*)(As + ldsoff));
      gld_lds16(Bt + (size_t)(n0 + row) * K + k0 + c8, (void*)(Bs + ldsoff));
    }
    __syncthreads();
    __builtin_amdgcn_s_setprio(1);
    for (int kp = 0; kp < 2; ++kp) {
      bf16x8 af[4], bfr[4];
      for (int mf = 0; mf < 4; ++mf)
        af[mf] = *(const bf16x8*)&As[(mi + mf * 16 + lrow) * 64 + kp * 32 + lk8];
      for (int nf = 0; nf < 4; ++nf)
        bfr[nf] = *(const bf16x8*)&Bs[(ni + nf * 16 + lrow) * 64 + kp * 32 + lk8];
      for (int mf = 0; mf < 4; ++mf)
        for (int nf = 0; nf < 4; ++nf)
          acc[mf][nf] = MFMA(af[mf], bfr[nf], acc[mf][nf]);
    }
    __builtin_amdgcn_s_setprio(0);
    __syncthreads();
  }

  for (int mf = 0; mf < 4; ++mf)
    for (int nf = 0; nf < 4; ++nf)
      for (int r = 0; r < 4; ++r) {
        int row = m0 + mi + mf * 16 + (l >> 4) * 4 + r;
        int col = n0 + ni + nf * 16 + lrow;
        float v = acc[mf][nf][r];
        if (col < 1024) {
          C0[(size_t)row * 1024 + col] = f2bf(v);
        } else {
          int b = row >> 11, n = row & 2047;
          int cv = col - 1024, h = cv >> 6, d = cv & 63;
          C1[(((size_t)(b * 8 + h) * 64 + d) << 11) + n] = f2bf(v);
        }
      }
}

// ---------------------------------------------------------------------------
// Output-projection GEMM, 64x128 tile (512 blocks -> 2 blocks/CU):
// Cf[8192,512] = A[8192,512] @ Wot[512,512]^T + bias
__global__ __launch_bounds__(256) void gemm_out(const short* __restrict__ A,
                                                const short* __restrict__ Bt,
                                                float* __restrict__ Cf,
                                                const float* __restrict__ bias) {
  __shared__ short As[64 * 64];
  __shared__ short Bs[128 * 64];
  const int tid = threadIdx.x;
  const int w = tid >> 6, l = tid & 63;
  const int m0 = blockIdx.x * 64, n0 = blockIdx.y * 128;
  const int mi = (w >> 1) * 32, ni = (w & 1) * 64;
  const int lrow = l & 15, lk8 = (l >> 4) * 8;
  const int K = 512, N = 512;

  f32x4 acc[2][4] = {};

  for (int k0 = 0; k0 < K; k0 += 64) {
    for (int g = 0; g < 2; ++g) {
      int c = g * 256 + tid;
      int row = c >> 3, c8 = (c & 7) * 8;
      gld_lds16(A + (size_t)(m0 + row) * K + k0 + c8, (void*)(As + c * 8));
    }
    for (int g = 0; g < 4; ++g) {
      int c = g * 256 + tid;
      int row = c >> 3, c8 = (c & 7) * 8;
      gld_lds16(Bt + (size_t)(n0 + row) * K + k0 + c8, (void*)(Bs + c * 8));
    }
    __syncthreads();
    __builtin_amdgcn_s_setprio(1);
    for (int kp = 0; kp < 2; ++kp) {
      bf16x8 af[2], bfr[4];
      for (int mf = 0; mf < 2; ++mf)
        af[mf] = *(const bf16x8*)&As[(mi + mf * 16 + lrow) * 64 + kp * 32 + lk8];
      for (int nf = 0; nf < 4; ++nf)
        bfr[nf] = *(const bf16x8*)&Bs[(ni + nf * 16 + lrow) * 64 + kp * 32 + lk8];
      for (int mf = 0; mf < 2; ++mf)
        for (int nf = 0; nf < 4; ++nf)
          acc[mf][nf] = MFMA(af[mf], bfr[nf], acc[mf][nf]);
    }
    __builtin_amdgcn_s_setprio(0);
    __syncthreads();
  }

  for (int mf = 0; mf < 2; ++mf)
    for (int nf = 0; nf < 4; ++nf)
      for (int r = 0; r < 4; ++r) {
        int row = m0 + mi + mf * 16 + (l >> 4) * 4 + r;
        int col = n0 + ni + nf * 16 + lrow;
        Cf[(size_t)row * N + col] = acc[mf][nf][r] + bias[col];
      }
}

// ---------------------------------------------------------------------------
// Dual-stream flash attention, v6: R6 structure with unroll-x2 (static buffer
// indices) + fully hoisted LDS/global address bases. sw(nf*16+lrow,kc) =
// nf*1024 + [lrow*64 + (kc^(lrow&7))*8]: the XOR part is nf-independent, so
// each array needs ONE base register per chunk-class; nf and the (static)
// buffer become ds_read imm offsets.
__global__ __launch_bounds__(256) void attn_kernel(
    const short* __restrict__ QK1, const short* __restrict__ QK2,
    const short* __restrict__ Vt1, const short* __restrict__ Vt2,
    short* __restrict__ Ocat) {
  __shared__ short K1s[2][4096], K2s[2][4096], V1s[2][4096], V2s[2][4096];

  const int tid = threadIdx.x;
  const int w = tid >> 6, l = tid & 63;
  const int qb = blockIdx.x, bh = blockIdx.y;
  const int b = bh >> 3, h = bh & 7;
  const int lrow = l & 15, g4 = l >> 4, lk8 = g4 * 8;

  const short* Q1p = QK1 + (size_t)b * 2048 * 1024 + h * 64;
  const short* K1p = Q1p + 512;
  const short* Q2p = QK2 + (size_t)b * 2048 * 1024 + h * 64;
  const short* K2p = Q2p + 512;
  const short* V1p = Vt1 + (size_t)bh * 64 * 2048;
  const short* V2p = Vt2 + (size_t)bh * 64 * 2048;

  // Q fragments in registers for the whole kernel
  const int qrow = qb * 64 + w * 16 + lrow;
  bf16x8 q1f0 = *(const bf16x8*)&Q1p[(size_t)qrow * 1024 + lk8];
  bf16x8 q1f1 = *(const bf16x8*)&Q1p[(size_t)qrow * 1024 + 32 + lk8];
  bf16x8 q2f0 = *(const bf16x8*)&Q2p[(size_t)qrow * 1024 + lk8];
  bf16x8 q2f1 = *(const bf16x8*)&Q2p[(size_t)qrow * 1024 + 32 + lk8];

  f32x4 o1[4] = {}, o2[4] = {};
  float mrun = -1e30f, lrun = 0.f;

  // ---- hoisted staging bases (per g-group), loop adds only the kt term ----
  const short* gK1[2]; const short* gK2[2];
  const short* gV1[2]; const short* gV2[2];
  short* dK1[2]; short* dK2[2]; short* dV1[2]; short* dV2[2];
#pragma unroll
  for (int gg = 0; gg < 2; ++gg) {
    int cl = gg * 256 + w * 64 + l;
    int row = cl >> 3;
    int lc = (cl & 7) ^ (row & 7);  // bank-conflict XOR swizzle (rule 21)
    // pi-permuted K row so the QK C-fragment lands in PV B-fragment layout
    int perm = (((row >> 4) & 1) << 5) + ((row & 12) << 1) +
               ((row >> 5) << 2) + (row & 3);
    gK1[gg] = K1p + (size_t)perm * 1024 + lc * 8;
    gK2[gg] = K2p + (size_t)perm * 1024 + lc * 8;
    gV1[gg] = V1p + (size_t)row * 2048 + lc * 8;
    gV2[gg] = V2p + (size_t)row * 2048 + lc * 8;
    dK1[gg] = &K1s[0][cl * 8];
    dK2[gg] = &K2s[0][cl * 8];
    dV1[gg] = &V1s[0][cl * 8];
    dV2[gg] = &V2s[0][cl * 8];
  }

  // ---- hoisted fragment-read bases (one per array per chunk-class) ----
  const int c0 = (g4 ^ (lrow & 7)) * 8;
  const int c1 = ((4 + g4) ^ (lrow & 7)) * 8;
  const int rb = lrow * 64;
  const short* rK1a = &K1s[0][rb + c0]; const short* rK1b = &K1s[0][rb + c1];
  const short* rK2a = &K2s[0][rb + c0]; const short* rK2b = &K2s[0][rb + c1];
  const short* rV1a = &V1s[0][rb + c0]; const short* rV1b = &V1s[0][rb + c1];
  const short* rV2a = &V2s[0][rb + c0]; const short* rV2b = &V2s[0][rb + c1];

#define STAGE(BUF, KT)                                                        \
  {                                                                           \
    _Pragma("unroll") for (int gg = 0; gg < 2; ++gg) {                        \
      gld_lds16(gK1[gg] + (size_t)(KT) * 65536, dK1[gg] + (BUF) * 4096);      \
      gld_lds16(gK2[gg] + (size_t)(KT) * 65536, dK2[gg] + (BUF) * 4096);      \
      gld_lds16(gV1[gg] + (size_t)(KT) * 64, dV1[gg] + (BUF) * 4096);         \
      gld_lds16(gV2[gg] + (size_t)(KT) * 64, dV2[gg] + (BUF) * 4096);         \
    }                                                                         \
  }

#define QKSTEP(BUF, S)                                                        \
  {                                                                           \
    __builtin_amdgcn_s_setprio(1);                                            \
    _Pragma("unroll") for (int nf = 0; nf < 4; ++nf) {                        \
      bf16x8 k1a = *(const bf16x8*)(rK1a + (BUF)*4096 + nf * 1024);           \
      bf16x8 k1b = *(const bf16x8*)(rK1b + (BUF)*4096 + nf * 1024);           \
      bf16x8 k2a = *(const bf16x8*)(rK2a + (BUF)*4096 + nf * 1024);           \
      bf16x8 k2b = *(const bf16x8*)(rK2b + (BUF)*4096 + nf * 1024);           \
      S[nf] = MFMA(k1a, q1f0, S[nf]);                                         \
      S[nf] = MFMA(k1b, q1f1, S[nf]);                                         \
      S[nf] = MFMA(k2a, q2f0, S[nf]);                                         \
      S[nf] = MFMA(k2b, q2f1, S[nf]);                                         \
    }                                                                         \
    __builtin_amdgcn_s_setprio(0);                                            \
  }

#define PK2(a, b_) (__float22bfloat162_rn(float2{(a), (b_)}))

#define SMPV(BUF, S)                                                          \
  {                                                                           \
    float mx = S[0][0];                                                       \
    _Pragma("unroll") for (int nf = 0; nf < 4; ++nf)                          \
        _Pragma("unroll") for (int r = 0; r < 4; ++r) mx =                    \
        fmaxf(mx, S[nf][r]);                                                  \
    if (!__all(mx - mrun <= 8.0f)) {                                          \
      float rm = fmaxf(mx, __shfl_xor(mx, 16));                               \
      rm = fmaxf(rm, __shfl_xor(rm, 32));                                     \
      float newm = fmaxf(mrun, rm);                                           \
      float corr = __expf(mrun - newm);                                       \
      mrun = newm;                                                            \
      lrun *= corr;                                                           \
      _Pragma("unroll") for (int nf = 0; nf < 4; ++nf) {                      \
        o1[nf] *= corr;                                                       \
        o2[nf] *= corr;                                                       \
      }                                                                       \
    }                                                                         \
    float p[16];                                                              \
    _Pragma("unroll") for (int i = 0; i < 16; ++i) {                          \
      p[i] = __expf(S[i >> 2][i & 3] - mrun);                                 \
      lrun += p[i];                                                           \
    }                                                                         \
    __hip_bfloat162 h0 = PK2(p[0], p[1]), h1 = PK2(p[2], p[3]);               \
    __hip_bfloat162 h2 = PK2(p[8], p[9]), h3 = PK2(p[10], p[11]);             \
    __hip_bfloat162 h4 = PK2(p[4], p[5]), h5 = PK2(p[6], p[7]);               \
    __hip_bfloat162 h6 = PK2(p[12], p[13]), h7 = PK2(p[14], p[15]);           \
    i32x4 w0 = {*(int*)&h0, *(int*)&h1, *(int*)&h2, *(int*)&h3};              \
    i32x4 w1 = {*(int*)&h4, *(int*)&h5, *(int*)&h6, *(int*)&h7};              \
    bf16x8 pb0 = *(bf16x8*)&w0, pb1 = *(bf16x8*)&w1;                          \
    __builtin_amdgcn_s_setprio(1);                                            \
    _Pragma("unroll") for (int nf = 0; nf < 4; ++nf) {                        \
      bf16x8 v1a = *(const bf16x8*)(rV1a + (BUF)*4096 + nf * 1024);           \
      bf16x8 v1b = *(const bf16x8*)(rV1b + (BUF)*4096 + nf * 1024);           \
      bf16x8 v2a = *(const bf16x8*)(rV2a + (BUF)*4096 + nf * 1024);           \
      bf16x8 v2b = *(const bf16x8*)(rV2b + (BUF)*4096 + nf * 1024);           \
      o1[nf] = MFMA(v1a, pb0, o1[nf]);                                        \
      o1[nf] = MFMA(v1b, pb1, o1[nf]);                                        \
      o2[nf] = MFMA(v2a, pb0, o2[nf]);                                        \
      o2[nf] = MFMA(v2b, pb1, o2[nf]);                                        \
    }                                                                         \
    __builtin_amdgcn_s_setprio(0);                                            \
  }

  STAGE(0, 0);

  for (int tp = 0; tp < 16; ++tp) {
    // ---- even iter t=2tp, buffer 0 ----
    STAGE(1, 2 * tp + 1);
    asm volatile("s_waitcnt vmcnt(8)" ::: "memory");  // tile t landed
    __builtin_amdgcn_s_barrier();
    {
      f32x4 s[4] = {};
      QKSTEP(0, s);
      SMPV(0, s);
    }
    asm volatile("s_waitcnt lgkmcnt(0)" ::: "memory");
    __builtin_amdgcn_s_barrier();

    // ---- odd iter t=2tp+1, buffer 1 ----
    if (tp < 15) {
      STAGE(0, 2 * tp + 2);
      asm volatile("s_waitcnt vmcnt(8)" ::: "memory");
    } else {
      asm volatile("s_waitcnt vmcnt(0)" ::: "memory");
    }
    __builtin_amdgcn_s_barrier();
    {
      f32x4 s[4] = {};
      QKSTEP(1, s);
      SMPV(1, s);
    }
    asm volatile("s_waitcnt lgkmcnt(0)" ::: "memory");
    __builtin_amdgcn_s_barrier();
  }

  // epilogue: reduce per-lane partial lrun across the 4 g4-lanes of the row
  lrun += __shfl_xor(lrun, 16);
  lrun += __shfl_xor(lrun, 32);
  float inv = 1.0f / lrun;
  const size_t base1 = ((size_t)b * 4096 + qrow) * 512 + h * 64;
  const size_t base2 = base1 + (size_t)2048 * 512;
#pragma unroll
  for (int nf = 0; nf < 4; ++nf) {
    int d0 = nf * 16 + g4 * 4;
    s16x4 ov;
    ov.x = f2bf(o1[nf][0] * inv);
    ov.y = f2bf(o1[nf][1] * inv);
    ov.z = f2bf(o1[nf][2] * inv);
    ov.w = f2bf(o1[nf][3] * inv);
    *(s16x4*)&Ocat[base1 + d0] = ov;
    ov.x = f2bf(o2[nf][0] * inv);
    ov.y = f2bf(o2[nf][1] * inv);
    ov.z = f2bf(o2[nf][2] * inv);
    ov.w = f2bf(o2[nf][3] * inv);
    *(s16x4*)&Ocat[base2 + d0] = ov;
  }
}

// ---------------------------------------------------------------------------
extern "C" void kernel_launch(void* const* d_in, const int* in_sizes, int n_in,
                              void* d_out, int out_size, void* d_ws,
                              size_t ws_size, hipStream_t stream) {
  const float* x1 = (const float*)d_in[0];
  const float* x2 = (const float*)d_in[1];
  const float* Wq1 = (const float*)d_in[2];
  const float* Wq2 = (const float*)d_in[3];
  const float* Wo = (const float*)d_in[4];
  const float* bo = (const float*)d_in[5];
  float* out = (float*)d_out;

  // workspace layout (bf16 elements); total ~45.6 MB
  short* p = (short*)d_ws;
  short* xb1 = p;  p += (size_t)4096 * 512;
  short* xb2 = p;  p += (size_t)4096 * 512;
  short* W1t = p;  p += (size_t)1536 * 512;
  short* W2t = p;  p += (size_t)1536 * 512;
  short* Wot = p;  p += (size_t)512 * 512;
  short* QK1 = p;  p += (size_t)4096 * 1024;
  short* QK2 = p;  p += (size_t)4096 * 1024;
  short* Vt1 = p;  p += (size_t)2 * 8 * 64 * 2048;
  short* Vt2 = p;  p += (size_t)2 * 8 * 64 * 2048;
  short* Ocat = p; p += (size_t)8192 * 512;

  cast_bf16_dual<<<4096, 256, 0, stream>>>(x1, x2, xb1, xb2, 4096 * 512);
  cast_transpose3<<<7168, 256, 0, stream>>>(Wq1, Wq2, Wo, W1t, W2t, Wot);

  gemm_qkv<<<dim3(32, 24), 256, 0, stream>>>(xb1, xb2, W1t, W2t, QK1, QK2,
                                             Vt1, Vt2);

  attn_kernel<<<dim3(32, 16), 256, 0, stream>>>(QK1, QK2, Vt1, Vt2, Ocat);

  gemm_out<<<dim3(128, 4), 256, 0, stream>>>(Ocat, Wot, out, bo);
}